// Round 10
// baseline (262.338 us; speedup 1.0000x reference)
//
#include <hip/hip_runtime.h>
#include <math.h>

#define B_ 128
#define N_ 512
#define D_ 128
#define H_ 8
#define NORM_ 11.313708498984761f
#define SC_ 16.322324f            /* NORM * log2(e) */
#define HSC_ 32.644648f           /* NORM * 2 * log2(e) */
#define CLIP_ 10.0f
#define MASKC_ -3.0e38f
#define NEG_BIG_ -1.0e30f
#define L2E_ 1.4426950408889634f
#define LN2_ 0.6931471805599453f

typedef unsigned short ushortx;
typedef __attribute__((ext_vector_type(8))) short s8v;   // 8 bf16 = 4 VGPR
typedef __attribute__((ext_vector_type(4))) float f4v;   // mfma C/D

#define MFMA_ __builtin_amdgcn_mfma_f32_16x16x32_bf16

__device__ __forceinline__ unsigned short f2bf(float x) {
  union { float f; unsigned u; } v; v.f = x;
  unsigned r = v.u + 0x7fffu + ((v.u >> 16) & 1u);
  return (unsigned short)(r >> 16);
}
__device__ __forceinline__ float bf2f(ushortx u) {
  union { unsigned u; float f; } v; v.u = ((unsigned)u) << 16; return v.f;
}
__device__ __forceinline__ unsigned cvtpk(float lo, float hi) {
  unsigned r;
  asm("v_cvt_pk_bf16_f32 %0, %1, %2" : "=v"(r) : "v"(lo), "v"(hi));
  return r;
}
__device__ __forceinline__ float exp2_hw(float x) {
  float r; asm("v_exp_f32 %0, %1" : "=v"(r) : "v"(x)); return r;
}
__device__ __forceinline__ float log2_hw(float x) {
  float r; asm("v_log_f32 %0, %1" : "=v"(r) : "v"(x)); return r;
}
__device__ __forceinline__ float rcp_hw(float x) {
  float r; asm("v_rcp_f32 %0, %1" : "=v"(r) : "v"(x)); return r;
}
__device__ __forceinline__ float max3f(float a, float b, float c) {
  float r; asm("v_max3_f32 %0, %1, %2, %3" : "=v"(r) : "v"(a), "v"(b), "v"(c));
  return r;
}

// ---------------------------------------------------------------------------
// wfold2: WfoldT[c][k] (bf16; cols 256+ have W_out folded), WsbT = Wstep_bot^T*SC
// ---------------------------------------------------------------------------
__global__ __launch_bounds__(128)
void wfold2(const float* __restrict__ Wnode, const float* __restrict__ Wout,
            const float* __restrict__ Wstep, ushortx* __restrict__ WfT,
            ushortx* __restrict__ WsbT) {
  const int c = blockIdx.x;
  const int k = threadIdx.x;
  if (c < 256) {
    WfT[c * 128 + k] = f2bf(Wnode[k * 384 + c]);
  } else if (c < 384) {
    const int d = c - 256;
    float s = 0.f;
    #pragma unroll 4
    for (int j = 0; j < 128; ++j) s += Wnode[k * 384 + 256 + j] * Wout[d * 128 + j];
    WfT[c * 128 + k] = f2bf(s);
  } else {
    const int d = c - 384;
    WsbT[d * 128 + k] = f2bf(Wstep[(128 + k) * 128 + d] * SC_);
  }
}

// ---------------------------------------------------------------------------
// sortperm (fused T-build): per b, LDS atomicMin first-selection table, then
// order nodes by first-selection step. K[b][s] = mask prefix length at step s;
// n_orig[b][p] = original node id at sorted position p.
// ---------------------------------------------------------------------------
__global__ __launch_bounds__(512)
void sortperm(const int* __restrict__ seq, ushortx* __restrict__ K,
              ushortx* __restrict__ n_orig) {
  const int b = blockIdx.x;
  const int t = threadIdx.x;
  const int lane = t & 63, wv = t >> 6;
  __shared__ int Tl[512];
  __shared__ int wsum[8];
  __shared__ int tot_s;

  Tl[t] = 0x7fffffff;
  __syncthreads();
  const int node = seq[b * 512 + t];
  atomicMin(&Tl[node], t + 1);
  __syncthreads();

  const int f = (Tl[node] == t + 1) ? 1 : 0;          // first occurrence
  const unsigned long long bal = __ballot(f);
  const int excl = __popcll(bal & ((1ull << lane) - 1ull));
  if (lane == 0) wsum[wv] = __popcll(bal);
  __syncthreads();
  int woff = 0;
  #pragma unroll
  for (int i = 0; i < 8; ++i) woff += (i < wv) ? wsum[i] : 0;
  const int Kt = woff + excl;
  K[b * 512 + t] = (ushortx)Kt;
  if (f) n_orig[b * 512 + Kt] = (ushortx)node;
  if (t == 511) tot_s = Kt + f;

  const int g = (Tl[t] == 0x7fffffff) ? 1 : 0;        // never selected
  const unsigned long long bal2 = __ballot(g);
  const int excl2 = __popcll(bal2 & ((1ull << lane) - 1ull));
  const int w2 = __popcll(bal2);
  __syncthreads();
  if (lane == 0) wsum[wv] = w2;
  __syncthreads();
  int woff2 = 0;
  #pragma unroll
  for (int i = 0; i < 8; ++i) woff2 += (i < wv) ? wsum[i] : 0;
  if (g) n_orig[b * 512 + tot_s + woff2 + excl2] = (ushortx)t;
}

// ---------------------------------------------------------------------------
// proj_mfma: gathers E rows in sorted order, emits packed decode layouts:
//   gK [b][h][p][16], gVt [b][h][dk][p], lKt [b][p][128]   (p = sorted node)
// ---------------------------------------------------------------------------
__global__ __launch_bounds__(256)
void proj_mfma(const float* __restrict__ E, const ushortx* __restrict__ WfT,
               const ushortx* __restrict__ n_orig,
               ushortx* __restrict__ gK, ushortx* __restrict__ gVt,
               ushortx* __restrict__ lKt) {
  __shared__ ushortx S[64 * 216];
  const int tid = threadIdx.x;
  const int w = tid >> 6, l = tid & 63;
  const int m16 = l & 15, lg = l >> 4;
  const int b = blockIdx.x >> 3;
  const int n0 = (blockIdx.x & 7) * 64;
  const int p_row = n0 + w * 16 + m16;
  const int orig = (int)n_orig[b * 512 + p_row];
  const float* er = E + ((size_t)b * 512 + orig) * 128;

  s8v af[4];
  #pragma unroll
  for (int ks = 0; ks < 4; ++ks) {
    float4 f0 = *(const float4*)(er + ks * 32 + lg * 8);
    float4 f1 = *(const float4*)(er + ks * 32 + lg * 8 + 4);
    union { unsigned u[4]; s8v v; } au;
    au.u[0] = cvtpk(f0.x, f0.y); au.u[1] = cvtpk(f0.z, f0.w);
    au.u[2] = cvtpk(f1.x, f1.y); au.u[3] = cvtpk(f1.z, f1.w);
    af[ks] = au.v;
  }

  const int lrow = w * 16 + 4 * lg;
  #pragma unroll
  for (int half = 0; half < 2; ++half) {
    const int cb = half * 192;
    #pragma unroll
    for (int ct = 0; ct < 12; ++ct) {
      const int lc = ct * 16 + m16;
      f4v acc = {0.f, 0.f, 0.f, 0.f};
      #pragma unroll
      for (int ks = 0; ks < 4; ++ks) {
        const s8v bf = *(const s8v*)(WfT + (size_t)(cb + lc) * 128 + ks * 32 + lg * 8);
        acc = MFMA_(af[ks], bf, acc, 0, 0, 0);
      }
      const unsigned w01 = cvtpk(acc[0], acc[1]);
      const unsigned w23 = cvtpk(acc[2], acc[3]);
      S[(lrow + 0) * 216 + lc] = (ushortx)(w01 & 0xffffu);
      S[(lrow + 1) * 216 + lc] = (ushortx)(w01 >> 16);
      S[(lrow + 2) * 216 + lc] = (ushortx)(w23 & 0xffffu);
      S[(lrow + 3) * 216 + lc] = (ushortx)(w23 >> 16);
    }
    __syncthreads();

    if (half == 0) {
      #pragma unroll
      for (int it = 0; it < 4; ++it) {
        const int idx = it * 256 + tid;
        const int hh = idx >> 7, nn = (idx >> 1) & 63, hf = idx & 1;
        const uint4 v = *(const uint4*)(&S[nn * 216 + hh * 16 + hf * 8]);
        *(uint4*)(gK + (((size_t)(b * 8 + hh) * 512 + n0 + nn) * 16 + hf * 8)) = v;
      }
      #pragma unroll
      for (int it = 0; it < 2; ++it) {
        const int idx = it * 256 + tid;
        const int hh = idx >> 7, dk = (idx >> 3) & 15, n8 = (idx & 7) * 8;
        const int lc = 128 + hh * 16 + dk;
        unsigned wr[4];
        #pragma unroll
        for (int j = 0; j < 4; ++j)
          wr[j] = (unsigned)S[(n8 + 2 * j) * 216 + lc] |
                  ((unsigned)S[(n8 + 2 * j + 1) * 216 + lc] << 16);
        uint4 o; o.x = wr[0]; o.y = wr[1]; o.z = wr[2]; o.w = wr[3];
        *(uint4*)(gVt + (((size_t)(b * 8 + hh) * 16 + dk) * 512 + n0 + n8)) = o;
      }
    } else {
      #pragma unroll
      for (int it = 0; it < 4; ++it) {
        const int idx = it * 256 + tid;
        const int nn = idx >> 4, d8 = (idx & 15) * 8;
        const uint4 v = *(const uint4*)(&S[nn * 216 + 64 + d8]);
        *(uint4*)(lKt + ((size_t)(b * 512 + n0 + nn) * 128 + d8)) = v;
      }
      #pragma unroll
      for (int it = 0; it < 2; ++it) {
        const int idx = it * 256 + tid;
        const int hq = idx >> 7, dk = (idx >> 3) & 15, n8 = (idx & 7) * 8;
        const int lc = hq * 16 + dk;
        unsigned wr[4];
        #pragma unroll
        for (int j = 0; j < 4; ++j)
          wr[j] = (unsigned)S[(n8 + 2 * j) * 216 + lc] |
                  ((unsigned)S[(n8 + 2 * j + 1) * 216 + lc] << 16);
        uint4 o; o.x = wr[0]; o.y = wr[1]; o.z = wr[2]; o.w = wr[3];
        *(uint4*)(gVt + (((size_t)(b * 8 + 4 + hq) * 16 + dk) * 512 + n0 + n8)) = o;
      }
    }
    __syncthreads();
  }
}

// ---------------------------------------------------------------------------
// prep: fixed = mean(emb)@Wfix; Qb0[b] = bf16(SC*(fixed+Wp@Wstep));
//       Abuf = SC*(fixed + emb[b,sel0]@Wstep_top).  Matvecs spread over 512 thr.
// ---------------------------------------------------------------------------
__global__ __launch_bounds__(512)
void prep(const float* __restrict__ emb, const int* __restrict__ seq,
          const float* __restrict__ Wp, const float* __restrict__ Wfix,
          const float* __restrict__ Wstep, ushortx* __restrict__ Qb0,
          float* __restrict__ Abuf) {
  const int b = blockIdx.x;
  const int t = threadIdx.x;
  __shared__ float4 red4[16][33];
  __shared__ float mean[128];
  __shared__ float pfx[4][128], pc[4][128], pa[4][128];
  const int row0 = t >> 5, c4 = t & 31;
  const float* eb = emb + (size_t)b * 512 * 128;
  float4 acc = {0.f, 0.f, 0.f, 0.f};
  for (int it = 0; it < 32; ++it) {
    const float4 x = *(const float4*)(eb + (size_t)(it * 16 + row0) * 128 + c4 * 4);
    acc.x += x.x; acc.y += x.y; acc.z += x.z; acc.w += x.w;
  }
  red4[row0][c4] = acc;
  __syncthreads();
  if (t < 128) {
    const int c4b = t >> 2, j = t & 3;
    float s = 0.f;
    #pragma unroll
    for (int r = 0; r < 16; ++r) s += ((const float*)&red4[r][c4b])[j];
    mean[t] = s * (1.f / 512.f);
  }
  __syncthreads();
  {
    const int d = t & 127, part = t >> 7;
    const int sel0 = seq[b * N_];
    const float* ef = eb + (size_t)sel0 * 128;
    float fx = 0.f;
    for (int k = part * 32; k < part * 32 + 32; ++k) fx += mean[k] * Wfix[k * 128 + d];
    float c = 0.f;
    for (int k = part * 64; k < part * 64 + 64; ++k) c += Wp[k] * Wstep[k * 128 + d];
    float a = 0.f;
    for (int k = part * 32; k < part * 32 + 32; ++k) a += ef[k] * Wstep[k * 128 + d];
    pfx[part][d] = fx; pc[part][d] = c; pa[part][d] = a;
  }
  __syncthreads();
  if (t < 128) {
    const float fx = pfx[0][t] + pfx[1][t] + pfx[2][t] + pfx[3][t];
    const float c  = pc[0][t] + pc[1][t] + pc[2][t] + pc[3][t];
    const float a  = pa[0][t] + pa[1][t] + pa[2][t] + pa[3][t];
    Qb0[b * 128 + t] = f2bf((fx + c) * SC_);
    Abuf[b * 128 + t] = (fx + a) * SC_;
  }
}

__global__ void tail_seq(const int* __restrict__ seq, float* __restrict__ out,
                         int count) {
  const int i = blockIdx.x * 256 + threadIdx.x;
  if (i < count) out[(size_t)B_ * N_ * N_ + i] = (float)seq[i];
}

// ---------------------------------------------------------------------------
// decode: block = (b, 16-step window), 8 waves = 8 heads, sorted-node space.
// Phase 0: fused Q. Phase A: 2-chunk-batched QK/online-softmax/PV with prefix
// skip. Phase C: tile-granular skip + cheap tanh (round-8 MASKC fill).
// Write pass: round-8 form (max-tree log-softmax, all-tile reads, one burst).
// ---------------------------------------------------------------------------
__global__ __launch_bounds__(512, 8)
void decode_mfma(const ushortx* __restrict__ gK,
                 const ushortx* __restrict__ gVt,
                 const ushortx* __restrict__ lKt,
                 const float* __restrict__ emb,
                 const int* __restrict__ seq,
                 const ushortx* __restrict__ WsbT,
                 const float* __restrict__ Abuf,
                 const ushortx* __restrict__ Qb0,
                 const ushortx* __restrict__ Ksrt,
                 const ushortx* __restrict__ n_orig,
                 float* __restrict__ out) {
  const int id = blockIdx.x;
  const int xcd = id & 7, pos = id >> 3;
  const int b = xcd * 16 + (pos >> 5);
  const int s0 = (pos & 31) * 16;
  const int tid = threadIdx.x;
  const int w = tid >> 6, l = tid & 63;
  const int m16 = l & 15, lg = l >> 4;

  __shared__ ushortx logitsTb[512 * 26];        // bf16 [p][s], stride 26
  __shared__ ushortx ctxh[16][136];             // ctx staging -> heads later
  __shared__ ushortx Qt[16][136];
  __shared__ ushortx norig_l[512];
  __shared__ ushortx Ko[16];
  __shared__ int sel_l[16];
  __shared__ float Ab[128];

  norig_l[tid] = n_orig[b * 512 + tid];
  if (tid < 16) {
    Ko[tid] = Ksrt[b * 512 + s0 + tid];
    const int sg = s0 + tid;
    sel_l[tid] = (sg >= 1) ? seq[b * 512 + sg - 1] : 0;
  }
  if (tid < 128) Ab[tid] = Abuf[b * 128 + tid];
  __syncthreads();

  // ---- phase 0a: stage 16 ctx rows (bf16), 256 threads ----
  if (tid < 256) {
    const int row = tid >> 4, c8 = (tid & 15) * 8;
    const float* er = emb + ((size_t)b * 512 + sel_l[row]) * 128 + c8;
    float4 f0 = *(const float4*)(er);
    float4 f1 = *(const float4*)(er + 4);
    unsigned* dst = (unsigned*)&ctxh[row][c8];
    dst[0] = cvtpk(f0.x, f0.y); dst[1] = cvtpk(f0.z, f0.w);
    dst[2] = cvtpk(f1.x, f1.y); dst[3] = cvtpk(f1.z, f1.w);
  }
  __syncthreads();

  // ---- phase 0b: Q = ctx @ Wsb + Ab (per-wave head tile) ----
  const int h = w;
  {
    s8v aw[4];
    #pragma unroll
    for (int ks = 0; ks < 4; ++ks)
      aw[ks] = *(const s8v*)(WsbT + (size_t)(h * 16 + m16) * 128 + ks * 32 + lg * 8);
    f4v acc = {0.f, 0.f, 0.f, 0.f};
    #pragma unroll
    for (int ks = 0; ks < 4; ++ks) {
      const s8v bf = *(const s8v*)(&ctxh[m16][ks * 32 + lg * 8]);
      acc = MFMA_(aw[ks], bf, acc, 0, 0, 0);
    }
    const int d0 = h * 16 + 4 * lg;
    unsigned q01 = cvtpk(acc[0] + Ab[d0], acc[1] + Ab[d0 + 1]);
    unsigned q23 = cvtpk(acc[2] + Ab[d0 + 2], acc[3] + Ab[d0 + 3]);
    if (s0 == 0 && m16 == 0) {                // step 0 uses precomputed Q
      q01 = *(const unsigned*)(Qb0 + b * 128 + d0);
      q23 = *(const unsigned*)(Qb0 + b * 128 + d0 + 2);
    }
    unsigned* qdst = (unsigned*)&Qt[m16][d0];
    qdst[0] = q01; qdst[1] = q23;
  }
  __syncthreads();

  s8v qf = {};
  if (lg < 2) qf = *(const s8v*)(&Qt[m16][h * 16 + lg * 8]);

  const int K0i = (int)Ko[0], K15 = (int)Ko[15];
  const int chS2 = (K0i >> 5) & ~1;             // even start chunk (pairs)
  const int chClean = (K15 + 31) >> 5;
  const int Ks = (int)Ko[m16];
  const size_t bh = (size_t)(b * 8 + h);

  f4v Oacc = {0.f, 0.f, 0.f, 0.f};
  float m_run = NEG_BIG_, l_run = 0.f;
  const int nA0 = 8 * (m16 >> 2) + (m16 & 3);

  for (int ch = chS2; ch < 16; ch += 2) {
    const int base = ch * 32;
    s8v a0 = {}, a1 = {}, a2 = {}, a3 = {};
    if (lg < 2) {
      a0 = *(const s8v*)(gK + ((bh * 512 + base + nA0) * 16 + lg * 8));
      a1 = *(const s8v*)(gK + ((bh * 512 + base + nA0 + 4) * 16 + lg * 8));
      a2 = *(const s8v*)(gK + ((bh * 512 + base + 32 + nA0) * 16 + lg * 8));
      a3 = *(const s8v*)(gK + ((bh * 512 + base + 32 + nA0 + 4) * 16 + lg * 8));
    }
    const s8v av0 = *(const s8v*)(gVt + ((bh * 16 + m16) * 512 + base + lg * 8));
    const s8v av1 = *(const s8v*)(gVt + ((bh * 16 + m16) * 512 + base + 32 + lg * 8));

    f4v z = {0.f, 0.f, 0.f, 0.f};
    f4v st0 = MFMA_(a0, qf, z, 0, 0, 0);
    f4v st1 = MFMA_(a1, qf, z, 0, 0, 0);
    f4v st2 = MFMA_(a2, qf, z, 0, 0, 0);
    f4v st3 = MFMA_(a3, qf, z, 0, 0, 0);

    float cm = max3f(st0[0], st0[1], st0[2]);
    cm = max3f(cm, st0[3], st1[0]);
    cm = max3f(cm, st1[1], st1[2]);
    cm = max3f(cm, st1[3], st2[0]);
    cm = max3f(cm, st2[1], st2[2]);
    cm = max3f(cm, st2[3], st3[0]);
    cm = max3f(cm, st3[1], st3[2]);
    cm = fmaxf(cm, st3[3]);
    cm = fmaxf(cm, __shfl_xor(cm, 16));
    cm = fmaxf(cm, __shfl_xor(cm, 32));

    if (__any(cm > m_run + 8.0f)) {
      const float mn = fmaxf(m_run, cm);
      const float cr = exp2_hw(m_run - mn);
      m_run = mn; l_run *= cr;
      Oacc[0] *= cr; Oacc[1] *= cr; Oacc[2] *= cr; Oacc[3] *= cr;
    }

    float p[16];
    #pragma unroll
    for (int r = 0; r < 4; ++r) {
      p[r]      = exp2_hw(st0[r] - m_run);
      p[4 + r]  = exp2_hw(st1[r] - m_run);
      p[8 + r]  = exp2_hw(st2[r] - m_run);
      p[12 + r] = exp2_hw(st3[r] - m_run);
    }
    if (ch < chClean) {                         // boundary: post-exp zeroing
      const int nb0 = base + 8 * lg;
      const int nb1 = base + 32 + 8 * lg;
      #pragma unroll
      for (int j = 0; j < 8; ++j) {
        p[j]     = (nb0 + j < Ks) ? 0.f : p[j];
        p[8 + j] = (nb1 + j < Ks) ? 0.f : p[8 + j];
      }
    }
    l_run += (((p[0] + p[1]) + (p[2] + p[3])) + ((p[4] + p[5]) + (p[6] + p[7]))) +
             (((p[8] + p[9]) + (p[10] + p[11])) + ((p[12] + p[13]) + (p[14] + p[15])));
    union { unsigned u[4]; s8v v; } pu0, pu1;
    pu0.u[0] = cvtpk(p[0], p[1]);  pu0.u[1] = cvtpk(p[2], p[3]);
    pu0.u[2] = cvtpk(p[4], p[5]);  pu0.u[3] = cvtpk(p[6], p[7]);
    pu1.u[0] = cvtpk(p[8], p[9]);  pu1.u[1] = cvtpk(p[10], p[11]);
    pu1.u[2] = cvtpk(p[12], p[13]); pu1.u[3] = cvtpk(p[14], p[15]);
    Oacc = MFMA_(av0, pu0.v, Oacc, 0, 0, 0);
    Oacc = MFMA_(av1, pu1.v, Oacc, 0, 0, 0);
  }

  l_run += __shfl_xor(l_run, 16);
  l_run += __shfl_xor(l_run, 32);
  const float scale = rcp_hw(l_run) * HSC_;
  {
    const int d0 = h * 16 + 4 * lg;
    unsigned* hd = (unsigned*)&ctxh[m16][d0];   // reuse ctxh as heads
    hd[0] = cvtpk(Oacc[0] * scale, Oacc[1] * scale);
    hd[1] = cvtpk(Oacc[2] * scale, Oacc[3] * scale);
  }
  __syncthreads();

  // ---- phase C: logits^T[p][s] = mfma(lKt rows, heads cols), tile skip ----
  #pragma unroll
  for (int nt = 0; nt < 4; ++nt) {
    const int n0 = w * 64 + nt * 16;
    if (n0 + 16 <= K0i) {                       // fully masked tile
      #pragma unroll
      for (int r = 0; r < 4; ++r)
        logitsTb[(n0 + 4 * lg + r) * 26 + m16] = f2bf(MASKC_);
      continue;
    }
    f4v acc = {0.f, 0.f, 0.f, 0.f};
    #pragma unroll
    for (int ks = 0; ks < 4; ++ks) {
      const s8v aL = *(const s8v*)(lKt + ((size_t)b * 512 + n0 + m16) * 128 + ks * 32 + lg * 8);
      const s8v bH = *(const s8v*)(&ctxh[m16][ks * 32 + lg * 8]);
      acc = MFMA_(aL, bH, acc, 0, 0, 0);
    }
    const bool bnd = (n0 < K15);
    #pragma unroll
    for (int r = 0; r < 4; ++r) {
      const int p = n0 + 4 * lg + r;
      const float e2 = exp2_hw(acc[r]);         // acc = 2*log2e*NORM*x
      float lgv = fmaf(-2.f * CLIP_, rcp_hw(e2 + 1.f), CLIP_);
      if (bnd && p < Ks) lgv = MASKC_;
      logitsTb[p * 26 + m16] = f2bf(lgv);
    }
  }
  __syncthreads();

  // ---- log_softmax over p per step; single-wave full-row writes ----
  int no[8];
  #pragma unroll
  for (int i = 0; i < 8; ++i) no[i] = (int)norig_l[i * 64 + l];
  #pragma unroll
  for (int pass = 0; pass < 2; ++pass) {
    const int s = w + pass * 8;
    float v[8];
    #pragma unroll
    for (int i = 0; i < 8; ++i) v[i] = bf2f(logitsTb[(i * 64 + l) * 26 + s]);
    float mm = max3f(v[0], v[1], v[2]);
    mm = max3f(mm, v[3], v[4]);
    mm = max3f(mm, v[5], v[6]);
    mm = fmaxf(mm, v[7]);
    #pragma unroll
    for (int off = 1; off <= 32; off <<= 1) mm = fmaxf(mm, __shfl_xor(mm, off));
    float es = 0.f;
    #pragma unroll
    for (int i = 0; i < 8; ++i) es += exp2_hw((v[i] - mm) * L2E_);
    #pragma unroll
    for (int off = 1; off <= 32; off <<= 1) es += __shfl_xor(es, off);
    const float logZ = mm + LN2_ * log2_hw(es);
    float* orow = out + ((size_t)(b * N_ + s0 + s)) * N_;
    #pragma unroll
    for (int i = 0; i < 8; ++i)
      orow[no[i]] = fmaxf(v[i] - logZ, NEG_BIG_);
  }
}

// ---------------------------------------------------------------------------
extern "C" void kernel_launch(void* const* d_in, const int* in_sizes, int n_in,
                              void* d_out, int out_size, void* d_ws, size_t ws_size,
                              hipStream_t stream) {
  const float* emb   = (const float*)d_in[0];
  const int*   seq   = (const int*)d_in[1];
  const float* Wp    = (const float*)d_in[2];
  const float* Wnode = (const float*)d_in[3];
  const float* Wfix  = (const float*)d_in[4];
  const float* Wstep = (const float*)d_in[5];
  const float* Wout  = (const float*)d_in[6];
  float* out = (float*)d_out;

  ushortx* gK    = (ushortx*)d_ws;                       // 8388608 u16
  ushortx* gVt   = gK   + (size_t)8388608;               // 8388608 u16
  ushortx* lKt   = gVt  + (size_t)8388608;               // 8388608 u16
  ushortx* WfT   = lKt  + (size_t)8388608;               //   49152 u16
  ushortx* WsbT  = WfT  + (size_t)49152;                 //   16384 u16
  ushortx* Ksrt  = WsbT + (size_t)16384;                 //   65536 u16
  ushortx* n_or  = Ksrt + (size_t)65536;                 //   65536 u16
  ushortx* Qb0   = n_or + (size_t)65536;                 //   16384 u16
  float*   Abuf  = (float*)(Qb0 + (size_t)16384);        //   16384 f32

  wfold2<<<512, 128, 0, stream>>>(Wnode, Wout, Wstep, WfT, WsbT);
  sortperm<<<128, 512, 0, stream>>>(seq, Ksrt, n_or);
  proj_mfma<<<1024, 256, 0, stream>>>(emb, WfT, n_or, gK, gVt, lKt);
  prep<<<128, 512, 0, stream>>>(emb, seq, Wp, Wfix, Wstep, Qb0, Abuf);
  decode_mfma<<<4096, 512, 0, stream>>>(gK, gVt, lKt, emb, seq, WsbT, Abuf,
                                        Qb0, Ksrt, n_or, out);

  const long long lp_elems = (long long)B_ * N_ * N_;
  const int tail = (int)((long long)out_size - lp_elems);
  if (tail > 0) {
    tail_seq<<<(tail + 255) / 256, 256, 0, stream>>>(seq, out, tail);
  }
}

// Round 11
// 240.423 us; speedup vs baseline: 1.0912x; 1.0912x over previous
//
#include <hip/hip_runtime.h>
#include <math.h>

#define B_ 128
#define N_ 512
#define D_ 128
#define H_ 8
#define NORM_ 11.313708498984761f
#define SC_ 16.322324f            /* NORM * log2(e) */
#define HSC_ 32.644648f           /* NORM * 2 * log2(e) */
#define CLIP_ 10.0f
#define MASKC_ -3.0e38f
#define NEG_BIG_ -1.0e30f
#define L2E_ 1.4426950408889634f
#define LN2_ 0.6931471805599453f

typedef unsigned short ushortx;
typedef __attribute__((ext_vector_type(8))) short s8v;   // 8 bf16 = 4 VGPR
typedef __attribute__((ext_vector_type(4))) float f4v;   // mfma C/D

#define MFMA_ __builtin_amdgcn_mfma_f32_16x16x32_bf16

__device__ __forceinline__ unsigned short f2bf(float x) {
  union { float f; unsigned u; } v; v.f = x;
  unsigned r = v.u + 0x7fffu + ((v.u >> 16) & 1u);
  return (unsigned short)(r >> 16);
}
__device__ __forceinline__ float bf2f(ushortx u) {
  union { unsigned u; float f; } v; v.u = ((unsigned)u) << 16; return v.f;
}
__device__ __forceinline__ unsigned cvtpk(float lo, float hi) {
  unsigned r;
  asm("v_cvt_pk_bf16_f32 %0, %1, %2" : "=v"(r) : "v"(lo), "v"(hi));
  return r;
}
__device__ __forceinline__ float exp2_hw(float x) {
  float r; asm("v_exp_f32 %0, %1" : "=v"(r) : "v"(x)); return r;
}
__device__ __forceinline__ float log2_hw(float x) {
  float r; asm("v_log_f32 %0, %1" : "=v"(r) : "v"(x)); return r;
}
__device__ __forceinline__ float rcp_hw(float x) {
  float r; asm("v_rcp_f32 %0, %1" : "=v"(r) : "v"(x)); return r;
}
__device__ __forceinline__ float max3f(float a, float b, float c) {
  float r; asm("v_max3_f32 %0, %1, %2, %3" : "=v"(r) : "v"(a), "v"(b), "v"(c));
  return r;
}

// ---------------------------------------------------------------------------
// wfold2: WfoldT[c][k] (bf16; cols 256+ have W_out folded), WsbT = Wstep_bot^T*SC
// ---------------------------------------------------------------------------
__global__ __launch_bounds__(128)
void wfold2(const float* __restrict__ Wnode, const float* __restrict__ Wout,
            const float* __restrict__ Wstep, ushortx* __restrict__ WfT,
            ushortx* __restrict__ WsbT) {
  const int c = blockIdx.x;
  const int k = threadIdx.x;
  if (c < 256) {
    WfT[c * 128 + k] = f2bf(Wnode[k * 384 + c]);
  } else if (c < 384) {
    const int d = c - 256;
    float s = 0.f;
    #pragma unroll 4
    for (int j = 0; j < 128; ++j) s += Wnode[k * 384 + 256 + j] * Wout[d * 128 + j];
    WfT[c * 128 + k] = f2bf(s);
  } else {
    const int d = c - 384;
    WsbT[d * 128 + k] = f2bf(Wstep[(128 + k) * 128 + d] * SC_);
  }
}

// ---------------------------------------------------------------------------
// sortperm (fused T-build): per b, LDS atomicMin first-selection table, then
// order nodes by first-selection step. K[b][s] = mask prefix length at step s;
// n_orig[b][p] = original node id at sorted position p.
// ---------------------------------------------------------------------------
__global__ __launch_bounds__(512)
void sortperm(const int* __restrict__ seq, ushortx* __restrict__ K,
              ushortx* __restrict__ n_orig) {
  const int b = blockIdx.x;
  const int t = threadIdx.x;
  const int lane = t & 63, wv = t >> 6;
  __shared__ int Tl[512];
  __shared__ int wsum[8];
  __shared__ int tot_s;

  Tl[t] = 0x7fffffff;
  __syncthreads();
  const int node = seq[b * 512 + t];
  atomicMin(&Tl[node], t + 1);
  __syncthreads();

  const int f = (Tl[node] == t + 1) ? 1 : 0;          // first occurrence
  const unsigned long long bal = __ballot(f);
  const int excl = __popcll(bal & ((1ull << lane) - 1ull));
  if (lane == 0) wsum[wv] = __popcll(bal);
  __syncthreads();
  int woff = 0;
  #pragma unroll
  for (int i = 0; i < 8; ++i) woff += (i < wv) ? wsum[i] : 0;
  const int Kt = woff + excl;
  K[b * 512 + t] = (ushortx)Kt;
  if (f) n_orig[b * 512 + Kt] = (ushortx)node;
  if (t == 511) tot_s = Kt + f;

  const int g = (Tl[t] == 0x7fffffff) ? 1 : 0;        // never selected
  const unsigned long long bal2 = __ballot(g);
  const int excl2 = __popcll(bal2 & ((1ull << lane) - 1ull));
  const int w2 = __popcll(bal2);
  __syncthreads();
  if (lane == 0) wsum[wv] = w2;
  __syncthreads();
  int woff2 = 0;
  #pragma unroll
  for (int i = 0; i < 8; ++i) woff2 += (i < wv) ? wsum[i] : 0;
  if (g) n_orig[b * 512 + tot_s + woff2 + excl2] = (ushortx)t;
}

// ---------------------------------------------------------------------------
// proj_mfma: gathers E rows in sorted order, emits packed decode layouts:
//   gK [b][h][p][16], gVt [b][h][dk][p], lKt [b][p][128]   (p = sorted node)
// ---------------------------------------------------------------------------
__global__ __launch_bounds__(256)
void proj_mfma(const float* __restrict__ E, const ushortx* __restrict__ WfT,
               const ushortx* __restrict__ n_orig,
               ushortx* __restrict__ gK, ushortx* __restrict__ gVt,
               ushortx* __restrict__ lKt) {
  __shared__ ushortx S[64 * 216];
  const int tid = threadIdx.x;
  const int w = tid >> 6, l = tid & 63;
  const int m16 = l & 15, lg = l >> 4;
  const int b = blockIdx.x >> 3;
  const int n0 = (blockIdx.x & 7) * 64;
  const int p_row = n0 + w * 16 + m16;
  const int orig = (int)n_orig[b * 512 + p_row];
  const float* er = E + ((size_t)b * 512 + orig) * 128;

  s8v af[4];
  #pragma unroll
  for (int ks = 0; ks < 4; ++ks) {
    float4 f0 = *(const float4*)(er + ks * 32 + lg * 8);
    float4 f1 = *(const float4*)(er + ks * 32 + lg * 8 + 4);
    union { unsigned u[4]; s8v v; } au;
    au.u[0] = cvtpk(f0.x, f0.y); au.u[1] = cvtpk(f0.z, f0.w);
    au.u[2] = cvtpk(f1.x, f1.y); au.u[3] = cvtpk(f1.z, f1.w);
    af[ks] = au.v;
  }

  const int lrow = w * 16 + 4 * lg;
  #pragma unroll
  for (int half = 0; half < 2; ++half) {
    const int cb = half * 192;
    #pragma unroll
    for (int ct = 0; ct < 12; ++ct) {
      const int lc = ct * 16 + m16;
      f4v acc = {0.f, 0.f, 0.f, 0.f};
      #pragma unroll
      for (int ks = 0; ks < 4; ++ks) {
        const s8v bf = *(const s8v*)(WfT + (size_t)(cb + lc) * 128 + ks * 32 + lg * 8);
        acc = MFMA_(af[ks], bf, acc, 0, 0, 0);
      }
      const unsigned w01 = cvtpk(acc[0], acc[1]);
      const unsigned w23 = cvtpk(acc[2], acc[3]);
      S[(lrow + 0) * 216 + lc] = (ushortx)(w01 & 0xffffu);
      S[(lrow + 1) * 216 + lc] = (ushortx)(w01 >> 16);
      S[(lrow + 2) * 216 + lc] = (ushortx)(w23 & 0xffffu);
      S[(lrow + 3) * 216 + lc] = (ushortx)(w23 >> 16);
    }
    __syncthreads();

    if (half == 0) {
      #pragma unroll
      for (int it = 0; it < 4; ++it) {
        const int idx = it * 256 + tid;
        const int hh = idx >> 7, nn = (idx >> 1) & 63, hf = idx & 1;
        const uint4 v = *(const uint4*)(&S[nn * 216 + hh * 16 + hf * 8]);
        *(uint4*)(gK + (((size_t)(b * 8 + hh) * 512 + n0 + nn) * 16 + hf * 8)) = v;
      }
      #pragma unroll
      for (int it = 0; it < 2; ++it) {
        const int idx = it * 256 + tid;
        const int hh = idx >> 7, dk = (idx >> 3) & 15, n8 = (idx & 7) * 8;
        const int lc = 128 + hh * 16 + dk;
        unsigned wr[4];
        #pragma unroll
        for (int j = 0; j < 4; ++j)
          wr[j] = (unsigned)S[(n8 + 2 * j) * 216 + lc] |
                  ((unsigned)S[(n8 + 2 * j + 1) * 216 + lc] << 16);
        uint4 o; o.x = wr[0]; o.y = wr[1]; o.z = wr[2]; o.w = wr[3];
        *(uint4*)(gVt + (((size_t)(b * 8 + hh) * 16 + dk) * 512 + n0 + n8)) = o;
      }
    } else {
      #pragma unroll
      for (int it = 0; it < 4; ++it) {
        const int idx = it * 256 + tid;
        const int nn = idx >> 4, d8 = (idx & 15) * 8;
        const uint4 v = *(const uint4*)(&S[nn * 216 + 64 + d8]);
        *(uint4*)(lKt + ((size_t)(b * 512 + n0 + nn) * 128 + d8)) = v;
      }
      #pragma unroll
      for (int it = 0; it < 2; ++it) {
        const int idx = it * 256 + tid;
        const int hq = idx >> 7, dk = (idx >> 3) & 15, n8 = (idx & 7) * 8;
        const int lc = hq * 16 + dk;
        unsigned wr[4];
        #pragma unroll
        for (int j = 0; j < 4; ++j)
          wr[j] = (unsigned)S[(n8 + 2 * j) * 216 + lc] |
                  ((unsigned)S[(n8 + 2 * j + 1) * 216 + lc] << 16);
        uint4 o; o.x = wr[0]; o.y = wr[1]; o.z = wr[2]; o.w = wr[3];
        *(uint4*)(gVt + (((size_t)(b * 8 + 4 + hq) * 16 + dk) * 512 + n0 + n8)) = o;
      }
    }
    __syncthreads();
  }
}

// ---------------------------------------------------------------------------
// prep: fixed = mean(emb)@Wfix; Qb0[b] = bf16(SC*(fixed+Wp@Wstep));
//       Abuf = SC*(fixed + emb[b,sel0]@Wstep_top)
// ---------------------------------------------------------------------------
__global__ __launch_bounds__(512)
void prep(const float* __restrict__ emb, const int* __restrict__ seq,
          const float* __restrict__ Wp, const float* __restrict__ Wfix,
          const float* __restrict__ Wstep, ushortx* __restrict__ Qb0,
          float* __restrict__ Abuf) {
  const int b = blockIdx.x;
  const int t = threadIdx.x;
  __shared__ float4 red4[16][33];
  __shared__ float mean[128];
  const int row0 = t >> 5, c4 = t & 31;
  const float* eb = emb + (size_t)b * 512 * 128;
  float4 acc = {0.f, 0.f, 0.f, 0.f};
  for (int it = 0; it < 32; ++it) {
    const float4 x = *(const float4*)(eb + (size_t)(it * 16 + row0) * 128 + c4 * 4);
    acc.x += x.x; acc.y += x.y; acc.z += x.z; acc.w += x.w;
  }
  red4[row0][c4] = acc;
  __syncthreads();
  if (t < 128) {
    const int c4b = t >> 2, j = t & 3;
    float s = 0.f;
    #pragma unroll
    for (int r = 0; r < 16; ++r) s += ((const float*)&red4[r][c4b])[j];
    mean[t] = s * (1.f / 512.f);
  }
  __syncthreads();
  if (t < 128) {
    float fx = 0.f;
    for (int k = 0; k < 128; ++k) fx += mean[k] * Wfix[k * 128 + t];
    float c = 0.f;
    for (int k = 0; k < 256; ++k) c += Wp[k] * Wstep[k * 128 + t];
    const int sel0 = seq[b * N_];
    const float* ef = eb + (size_t)sel0 * 128;
    float a = 0.f;
    for (int k = 0; k < 128; ++k) a += ef[k] * Wstep[k * 128 + t];
    Qb0[b * 128 + t] = f2bf((fx + c) * SC_);
    Abuf[b * 128 + t] = (fx + a) * SC_;
  }
}

__global__ void tail_seq(const int* __restrict__ seq, float* __restrict__ out,
                         int count) {
  const int i = blockIdx.x * 256 + threadIdx.x;
  if (i < count) out[(size_t)B_ * N_ * N_ + i] = (float)seq[i];
}

// ---------------------------------------------------------------------------
// decode: block = (b, 16-step window), 8 waves = 8 heads, sorted-node space.
// Phase 0: fused Q (ctx staged in LDS bf16, mfma vs WsbT).
// Phase A: QK/online-softmax/PV, prefix-mask skip (1-chunk loop).
// Phase C: logits -> bf16 LDS [p][s]; per-wave row log-softmax; single-wave
// row writes (full 2KB row per wave -> no partial-line RMW).
// ---------------------------------------------------------------------------
__global__ __launch_bounds__(512, 8)
void decode_mfma(const ushortx* __restrict__ gK,
                 const ushortx* __restrict__ gVt,
                 const ushortx* __restrict__ lKt,
                 const float* __restrict__ emb,
                 const int* __restrict__ seq,
                 const ushortx* __restrict__ WsbT,
                 const float* __restrict__ Abuf,
                 const ushortx* __restrict__ Qb0,
                 const ushortx* __restrict__ Ksrt,
                 const ushortx* __restrict__ n_orig,
                 float* __restrict__ out) {
  const int id = blockIdx.x;
  const int xcd = id & 7, pos = id >> 3;
  const int b = xcd * 16 + (pos >> 5);
  const int s0 = (pos & 31) * 16;
  const int tid = threadIdx.x;
  const int w = tid >> 6, l = tid & 63;
  const int m16 = l & 15, lg = l >> 4;

  __shared__ ushortx logitsTb[512 * 26];        // bf16 [p][s], stride 26
  __shared__ ushortx ctxh[16][136];             // ctx staging -> heads later
  __shared__ ushortx Qt[16][136];
  __shared__ ushortx norig_l[512];
  __shared__ ushortx Ko[16];
  __shared__ int sel_l[16];
  __shared__ float Ab[128];

  norig_l[tid] = n_orig[b * 512 + tid];
  if (tid < 16) {
    Ko[tid] = Ksrt[b * 512 + s0 + tid];
    const int sg = s0 + tid;
    sel_l[tid] = (sg >= 1) ? seq[b * 512 + sg - 1] : 0;
  }
  if (tid < 128) Ab[tid] = Abuf[b * 128 + tid];
  __syncthreads();

  // ---- phase 0a: stage 16 ctx rows (bf16), 256 threads ----
  if (tid < 256) {
    const int row = tid >> 4, c8 = (tid & 15) * 8;
    const float* er = emb + ((size_t)b * 512 + sel_l[row]) * 128 + c8;
    float4 f0 = *(const float4*)(er);
    float4 f1 = *(const float4*)(er + 4);
    unsigned* dst = (unsigned*)&ctxh[row][c8];
    dst[0] = cvtpk(f0.x, f0.y); dst[1] = cvtpk(f0.z, f0.w);
    dst[2] = cvtpk(f1.x, f1.y); dst[3] = cvtpk(f1.z, f1.w);
  }
  __syncthreads();

  // ---- phase 0b: Q = ctx @ Wsb + Ab (per-wave head tile) ----
  const int h = w;
  {
    s8v aw[4];
    #pragma unroll
    for (int ks = 0; ks < 4; ++ks)
      aw[ks] = *(const s8v*)(WsbT + (size_t)(h * 16 + m16) * 128 + ks * 32 + lg * 8);
    f4v acc = {0.f, 0.f, 0.f, 0.f};
    #pragma unroll
    for (int ks = 0; ks < 4; ++ks) {
      const s8v bf = *(const s8v*)(&ctxh[m16][ks * 32 + lg * 8]);
      acc = MFMA_(aw[ks], bf, acc, 0, 0, 0);
    }
    const int d0 = h * 16 + 4 * lg;
    unsigned q01 = cvtpk(acc[0] + Ab[d0], acc[1] + Ab[d0 + 1]);
    unsigned q23 = cvtpk(acc[2] + Ab[d0 + 2], acc[3] + Ab[d0 + 3]);
    if (s0 == 0 && m16 == 0) {                // step 0 uses precomputed Q
      q01 = *(const unsigned*)(Qb0 + b * 128 + d0);
      q23 = *(const unsigned*)(Qb0 + b * 128 + d0 + 2);
    }
    unsigned* qdst = (unsigned*)&Qt[m16][d0];
    qdst[0] = q01; qdst[1] = q23;
  }
  __syncthreads();

  s8v qf = {};
  if (lg < 2) qf = *(const s8v*)(&Qt[m16][h * 16 + lg * 8]);

  const int K0i = (int)Ko[0], K15 = (int)Ko[15];
  const int chStart = K0i >> 5;
  const int chClean = (K15 + 31) >> 5;
  const int Ks = (int)Ko[m16];
  const size_t bh = (size_t)(b * 8 + h);

  f4v Oacc = {0.f, 0.f, 0.f, 0.f};
  float m_run = NEG_BIG_, l_run = 0.f;
  const int nA0 = 8 * (m16 >> 2) + (m16 & 3);

  for (int ch = chStart; ch < 16; ++ch) {
    const int base = ch * 32;
    s8v a0 = {}, a1 = {};
    if (lg < 2) {
      a0 = *(const s8v*)(gK + ((bh * 512 + base + nA0) * 16 + lg * 8));
      a1 = *(const s8v*)(gK + ((bh * 512 + base + nA0 + 4) * 16 + lg * 8));
    }
    const s8v av = *(const s8v*)(gVt + ((bh * 16 + m16) * 512 + base + lg * 8));

    f4v z = {0.f, 0.f, 0.f, 0.f};
    f4v st0 = MFMA_(a0, qf, z, 0, 0, 0);
    f4v st1 = MFMA_(a1, qf, z, 0, 0, 0);

    float cm = max3f(st0[0], st0[1], st0[2]);
    cm = max3f(cm, st0[3], st1[0]);
    cm = max3f(cm, st1[1], st1[2]);
    cm = fmaxf(cm, st1[3]);
    cm = fmaxf(cm, __shfl_xor(cm, 16));
    cm = fmaxf(cm, __shfl_xor(cm, 32));

    if (__any(cm > m_run + 8.0f)) {
      const float mn = fmaxf(m_run, cm);
      const float cr = exp2_hw(m_run - mn);
      m_run = mn; l_run *= cr;
      Oacc[0] *= cr; Oacc[1] *= cr; Oacc[2] *= cr; Oacc[3] *= cr;
    }

    float p[8];
    #pragma unroll
    for (int r = 0; r < 4; ++r) {
      p[r]     = exp2_hw(st0[r] - m_run);
      p[4 + r] = exp2_hw(st1[r] - m_run);
    }
    if (ch < chClean) {
      const int nb = base + 8 * lg;
      #pragma unroll
      for (int j = 0; j < 8; ++j) p[j] = (nb + j < Ks) ? 0.f : p[j];
    }
    l_run += ((p[0] + p[1]) + (p[2] + p[3])) + ((p[4] + p[5]) + (p[6] + p[7]));
    union { unsigned u[4]; s8v v; } pu;
    pu.u[0] = cvtpk(p[0], p[1]); pu.u[1] = cvtpk(p[2], p[3]);
    pu.u[2] = cvtpk(p[4], p[5]); pu.u[3] = cvtpk(p[6], p[7]);
    Oacc = MFMA_(av, pu.v, Oacc, 0, 0, 0);
  }

  l_run += __shfl_xor(l_run, 16);
  l_run += __shfl_xor(l_run, 32);
  const float scale = rcp_hw(l_run) * HSC_;
  {
    const int d0 = h * 16 + 4 * lg;
    unsigned* hd = (unsigned*)&ctxh[m16][d0];   // reuse ctxh as heads
    hd[0] = cvtpk(Oacc[0] * scale, Oacc[1] * scale);
    hd[1] = cvtpk(Oacc[2] * scale, Oacc[3] * scale);
  }
  __syncthreads();

  // ---- phase C: logits^T[p][s] = mfma(lKt rows, heads cols), prefix skip ----
  #pragma unroll
  for (int nt = 0; nt < 4; ++nt) {
    const int n0 = w * 64 + nt * 16;
    if (n0 + 16 <= K0i) {                       // fully masked tile
      #pragma unroll
      for (int r = 0; r < 4; ++r)
        logitsTb[(n0 + 4 * lg + r) * 26 + m16] = f2bf(MASKC_);
      continue;
    }
    f4v acc = {0.f, 0.f, 0.f, 0.f};
    #pragma unroll
    for (int ks = 0; ks < 4; ++ks) {
      const s8v aL = *(const s8v*)(lKt + ((size_t)b * 512 + n0 + m16) * 128 + ks * 32 + lg * 8);
      const s8v bH = *(const s8v*)(&ctxh[m16][ks * 32 + lg * 8]);
      acc = MFMA_(aL, bH, acc, 0, 0, 0);
    }
    const bool bnd = (n0 < K15);
    #pragma unroll
    for (int r = 0; r < 4; ++r) {
      const int p = n0 + 4 * lg + r;
      float x = fminf(fmaxf(acc[r], -43.f), 43.f);   // = 2*log2e*real_x
      const float e2 = exp2_hw(x);
      float lgv = CLIP_ * (e2 - 1.f) * rcp_hw(e2 + 1.f);
      if (bnd && p < Ks) lgv = MASKC_;
      logitsTb[p * 26 + m16] = f2bf(lgv);
    }
  }
  __syncthreads();

  // ---- log_softmax over p per step; single-wave full-row writes ----
  int no[8];
  #pragma unroll
  for (int i = 0; i < 8; ++i) no[i] = (int)norig_l[i * 64 + l];
  #pragma unroll
  for (int pass = 0; pass < 2; ++pass) {
    const int s = w + pass * 8;
    float v[8];
    #pragma unroll
    for (int i = 0; i < 8; ++i) v[i] = bf2f(logitsTb[(i * 64 + l) * 26 + s]);
    float mm = max3f(v[0], v[1], v[2]);
    mm = max3f(mm, v[3], v[4]);
    mm = max3f(mm, v[5], v[6]);
    mm = fmaxf(mm, v[7]);
    #pragma unroll
    for (int off = 1; off <= 32; off <<= 1) mm = fmaxf(mm, __shfl_xor(mm, off));
    float es = 0.f;
    #pragma unroll
    for (int i = 0; i < 8; ++i) es += exp2_hw((v[i] - mm) * L2E_);
    #pragma unroll
    for (int off = 1; off <= 32; off <<= 1) es += __shfl_xor(es, off);
    const float logZ = mm + LN2_ * log2_hw(es);
    float* orow = out + ((size_t)(b * N_ + s0 + s)) * N_;
    #pragma unroll
    for (int i = 0; i < 8; ++i)
      orow[no[i]] = fmaxf(v[i] - logZ, NEG_BIG_);
  }
}

// ---------------------------------------------------------------------------
extern "C" void kernel_launch(void* const* d_in, const int* in_sizes, int n_in,
                              void* d_out, int out_size, void* d_ws, size_t ws_size,
                              hipStream_t stream) {
  const float* emb   = (const float*)d_in[0];
  const int*   seq   = (const int*)d_in[1];
  const float* Wp    = (const float*)d_in[2];
  const float* Wnode = (const float*)d_in[3];
  const float* Wfix  = (const float*)d_in[4];
  const float* Wstep = (const float*)d_in[5];
  const float* Wout  = (const float*)d_in[6];
  float* out = (float*)d_out;

  ushortx* gK    = (ushortx*)d_ws;                       // 8388608 u16
  ushortx* gVt   = gK   + (size_t)8388608;               // 8388608 u16
  ushortx* lKt   = gVt  + (size_t)8388608;               // 8388608 u16
  ushortx* WfT   = lKt  + (size_t)8388608;               //   49152 u16
  ushortx* WsbT  = WfT  + (size_t)49152;                 //   16384 u16
  ushortx* Ksrt  = WsbT + (size_t)16384;                 //   65536 u16
  ushortx* n_or  = Ksrt + (size_t)65536;                 //   65536 u16
  ushortx* Qb0   = n_or + (size_t)65536;                 //   16384 u16
  float*   Abuf  = (float*)(Qb0 + (size_t)16384);        //   16384 f32

  wfold2<<<512, 128, 0, stream>>>(Wnode, Wout, Wstep, WfT, WsbT);
  sortperm<<<128, 512, 0, stream>>>(seq, Ksrt, n_or);
  proj_mfma<<<1024, 256, 0, stream>>>(emb, WfT, n_or, gK, gVt, lKt);
  prep<<<128, 512, 0, stream>>>(emb, seq, Wp, Wfix, Wstep, Qb0, Abuf);
  decode_mfma<<<4096, 512, 0, stream>>>(gK, gVt, lKt, emb, seq, WsbT, Abuf,
                                        Qb0, Ksrt, n_or, out);

  const long long lp_elems = (long long)B_ * N_ * N_;
  const int tail = (int)((long long)out_size - lp_elems);
  if (tail > 0) {
    tail_seq<<<(tail + 255) / 256, 256, 0, stream>>>(seq, out, tail);
  }
}

// Round 12
// 238.254 us; speedup vs baseline: 1.1011x; 1.0091x over previous
//
#include <hip/hip_runtime.h>
#include <math.h>

#define B_ 128
#define N_ 512
#define D_ 128
#define H_ 8
#define NORM_ 11.313708498984761f
#define SC_ 16.322324f            /* NORM * log2(e) */
#define HSC_ 32.644648f           /* NORM * 2 * log2(e) */
#define CLIP_ 10.0f
#define MASKC_ -3.0e38f
#define NEG_BIG_ -1.0e30f
#define L2E_ 1.4426950408889634f
#define LN2_ 0.6931471805599453f

typedef unsigned short ushortx;
typedef __attribute__((ext_vector_type(8))) short s8v;   // 8 bf16 = 4 VGPR
typedef __attribute__((ext_vector_type(4))) float f4v;   // mfma C/D

#define MFMA_ __builtin_amdgcn_mfma_f32_16x16x32_bf16

__device__ __forceinline__ unsigned short f2bf(float x) {
  union { float f; unsigned u; } v; v.f = x;
  unsigned r = v.u + 0x7fffu + ((v.u >> 16) & 1u);
  return (unsigned short)(r >> 16);
}
__device__ __forceinline__ float bf2f(ushortx u) {
  union { unsigned u; float f; } v; v.u = ((unsigned)u) << 16; return v.f;
}
__device__ __forceinline__ unsigned cvtpk(float lo, float hi) {
  unsigned r;
  asm("v_cvt_pk_bf16_f32 %0, %1, %2" : "=v"(r) : "v"(lo), "v"(hi));
  return r;
}
__device__ __forceinline__ float exp2_hw(float x) {
  float r; asm("v_exp_f32 %0, %1" : "=v"(r) : "v"(x)); return r;
}
__device__ __forceinline__ float log2_hw(float x) {
  float r; asm("v_log_f32 %0, %1" : "=v"(r) : "v"(x)); return r;
}
__device__ __forceinline__ float rcp_hw(float x) {
  float r; asm("v_rcp_f32 %0, %1" : "=v"(r) : "v"(x)); return r;
}
__device__ __forceinline__ float max3f(float a, float b, float c) {
  float r; asm("v_max3_f32 %0, %1, %2, %3" : "=v"(r) : "v"(a), "v"(b), "v"(c));
  return r;
}

// ---------------------------------------------------------------------------
// prologue: 512 blocks x 512 thr, four independent regions by blockIdx:
//   [0,128):   wfold  -> WfT (bf16 WfoldT; cols 256+ have W_out folded), WsbT
//   [128,256): sortperm -> Ksrt, n_orig (LDS atomicMin first-selection table)
//   [256,384): prep -> Qb0, Abuf
//   [384,512): tail -> out[lp..] = float(seq)
// ---------------------------------------------------------------------------
__global__ __launch_bounds__(512)
void prologue(const float* __restrict__ emb, const int* __restrict__ seq,
              const float* __restrict__ Wp, const float* __restrict__ Wnode,
              const float* __restrict__ Wfix, const float* __restrict__ Wstep,
              const float* __restrict__ Wout,
              ushortx* __restrict__ WfT, ushortx* __restrict__ WsbT,
              ushortx* __restrict__ Ksrt, ushortx* __restrict__ n_orig,
              ushortx* __restrict__ Qb0, float* __restrict__ Abuf,
              float* __restrict__ out, int tail_count) {
  const int blk = blockIdx.x;
  const int t = threadIdx.x;

  if (blk < 128) {
    // ---- wfold ----
    const int c = blk * 4 + (t >> 7);
    const int k = t & 127;
    if (c < 256) {
      WfT[c * 128 + k] = f2bf(Wnode[k * 384 + c]);
    } else if (c < 384) {
      const int d = c - 256;
      float s = 0.f;
      #pragma unroll 4
      for (int j = 0; j < 128; ++j) s += Wnode[k * 384 + 256 + j] * Wout[d * 128 + j];
      WfT[c * 128 + k] = f2bf(s);
    } else {
      const int d = c - 384;
      WsbT[d * 128 + k] = f2bf(Wstep[(128 + k) * 128 + d] * SC_);
    }
    return;
  }

  if (blk < 256) {
    // ---- sortperm ----
    const int b = blk - 128;
    const int lane = t & 63, wv = t >> 6;
    __shared__ int Tl[512];
    __shared__ int wsum[8];
    __shared__ int tot_s;

    Tl[t] = 0x7fffffff;
    __syncthreads();
    const int node = seq[b * 512 + t];
    atomicMin(&Tl[node], t + 1);
    __syncthreads();

    const int f = (Tl[node] == t + 1) ? 1 : 0;
    const unsigned long long bal = __ballot(f);
    const int excl = __popcll(bal & ((1ull << lane) - 1ull));
    if (lane == 0) wsum[wv] = __popcll(bal);
    __syncthreads();
    int woff = 0;
    #pragma unroll
    for (int i = 0; i < 8; ++i) woff += (i < wv) ? wsum[i] : 0;
    const int Kt = woff + excl;
    Ksrt[b * 512 + t] = (ushortx)Kt;
    if (f) n_orig[b * 512 + Kt] = (ushortx)node;
    if (t == 511) tot_s = Kt + f;

    const int g = (Tl[t] == 0x7fffffff) ? 1 : 0;
    const unsigned long long bal2 = __ballot(g);
    const int excl2 = __popcll(bal2 & ((1ull << lane) - 1ull));
    const int w2 = __popcll(bal2);
    __syncthreads();
    if (lane == 0) wsum[wv] = w2;
    __syncthreads();
    int woff2 = 0;
    #pragma unroll
    for (int i = 0; i < 8; ++i) woff2 += (i < wv) ? wsum[i] : 0;
    if (g) n_orig[b * 512 + tot_s + woff2 + excl2] = (ushortx)t;
    return;
  }

  if (blk < 384) {
    // ---- prep ----
    const int b = blk - 256;
    __shared__ float4 red4[16][33];
    __shared__ float mean[128];
    const int row0 = t >> 5, c4 = t & 31;
    const float* eb = emb + (size_t)b * 512 * 128;
    float4 acc = {0.f, 0.f, 0.f, 0.f};
    for (int it = 0; it < 32; ++it) {
      const float4 x = *(const float4*)(eb + (size_t)(it * 16 + row0) * 128 + c4 * 4);
      acc.x += x.x; acc.y += x.y; acc.z += x.z; acc.w += x.w;
    }
    red4[row0][c4] = acc;
    __syncthreads();
    if (t < 128) {
      const int c4b = t >> 2, j = t & 3;
      float s = 0.f;
      #pragma unroll
      for (int r = 0; r < 16; ++r) s += ((const float*)&red4[r][c4b])[j];
      mean[t] = s * (1.f / 512.f);
    }
    __syncthreads();
    if (t < 128) {
      float fx = 0.f;
      for (int k = 0; k < 128; ++k) fx += mean[k] * Wfix[k * 128 + t];
      float c = 0.f;
      for (int k = 0; k < 256; ++k) c += Wp[k] * Wstep[k * 128 + t];
      const int sel0 = seq[b * N_];
      const float* ef = eb + (size_t)sel0 * 128;
      float a = 0.f;
      for (int k = 0; k < 128; ++k) a += ef[k] * Wstep[k * 128 + t];
      Qb0[b * 128 + t] = f2bf((fx + c) * SC_);
      Abuf[b * 128 + t] = (fx + a) * SC_;
    }
    return;
  }

  // ---- tail: out[lp + i] = float(seq[i]) ----
  {
    const int i = (blk - 384) * 512 + t;
    if (i < tail_count) out[(size_t)B_ * N_ * N_ + i] = (float)seq[i];
  }
}

// ---------------------------------------------------------------------------
// proj_mfma: gathers E rows in sorted order, emits packed decode layouts:
//   gK [b][h][p][16], gVt [b][h][dk][p], lKt [b][p][128]   (p = sorted node)
// ---------------------------------------------------------------------------
__global__ __launch_bounds__(256)
void proj_mfma(const float* __restrict__ E, const ushortx* __restrict__ WfT,
               const ushortx* __restrict__ n_orig,
               ushortx* __restrict__ gK, ushortx* __restrict__ gVt,
               ushortx* __restrict__ lKt) {
  __shared__ ushortx S[64 * 216];
  const int tid = threadIdx.x;
  const int w = tid >> 6, l = tid & 63;
  const int m16 = l & 15, lg = l >> 4;
  const int b = blockIdx.x >> 3;
  const int n0 = (blockIdx.x & 7) * 64;
  const int p_row = n0 + w * 16 + m16;
  const int orig = (int)n_orig[b * 512 + p_row];
  const float* er = E + ((size_t)b * 512 + orig) * 128;

  s8v af[4];
  #pragma unroll
  for (int ks = 0; ks < 4; ++ks) {
    float4 f0 = *(const float4*)(er + ks * 32 + lg * 8);
    float4 f1 = *(const float4*)(er + ks * 32 + lg * 8 + 4);
    union { unsigned u[4]; s8v v; } au;
    au.u[0] = cvtpk(f0.x, f0.y); au.u[1] = cvtpk(f0.z, f0.w);
    au.u[2] = cvtpk(f1.x, f1.y); au.u[3] = cvtpk(f1.z, f1.w);
    af[ks] = au.v;
  }

  const int lrow = w * 16 + 4 * lg;
  #pragma unroll
  for (int half = 0; half < 2; ++half) {
    const int cb = half * 192;
    #pragma unroll
    for (int ct = 0; ct < 12; ++ct) {
      const int lc = ct * 16 + m16;
      f4v acc = {0.f, 0.f, 0.f, 0.f};
      #pragma unroll
      for (int ks = 0; ks < 4; ++ks) {
        const s8v bf = *(const s8v*)(WfT + (size_t)(cb + lc) * 128 + ks * 32 + lg * 8);
        acc = MFMA_(af[ks], bf, acc, 0, 0, 0);
      }
      const unsigned w01 = cvtpk(acc[0], acc[1]);
      const unsigned w23 = cvtpk(acc[2], acc[3]);
      S[(lrow + 0) * 216 + lc] = (ushortx)(w01 & 0xffffu);
      S[(lrow + 1) * 216 + lc] = (ushortx)(w01 >> 16);
      S[(lrow + 2) * 216 + lc] = (ushortx)(w23 & 0xffffu);
      S[(lrow + 3) * 216 + lc] = (ushortx)(w23 >> 16);
    }
    __syncthreads();

    if (half == 0) {
      #pragma unroll
      for (int it = 0; it < 4; ++it) {
        const int idx = it * 256 + tid;
        const int hh = idx >> 7, nn = (idx >> 1) & 63, hf = idx & 1;
        const uint4 v = *(const uint4*)(&S[nn * 216 + hh * 16 + hf * 8]);
        *(uint4*)(gK + (((size_t)(b * 8 + hh) * 512 + n0 + nn) * 16 + hf * 8)) = v;
      }
      #pragma unroll
      for (int it = 0; it < 2; ++it) {
        const int idx = it * 256 + tid;
        const int hh = idx >> 7, dk = (idx >> 3) & 15, n8 = (idx & 7) * 8;
        const int lc = 128 + hh * 16 + dk;
        unsigned wr[4];
        #pragma unroll
        for (int j = 0; j < 4; ++j)
          wr[j] = (unsigned)S[(n8 + 2 * j) * 216 + lc] |
                  ((unsigned)S[(n8 + 2 * j + 1) * 216 + lc] << 16);
        uint4 o; o.x = wr[0]; o.y = wr[1]; o.z = wr[2]; o.w = wr[3];
        *(uint4*)(gVt + (((size_t)(b * 8 + hh) * 16 + dk) * 512 + n0 + n8)) = o;
      }
    } else {
      #pragma unroll
      for (int it = 0; it < 4; ++it) {
        const int idx = it * 256 + tid;
        const int nn = idx >> 4, d8 = (idx & 15) * 8;
        const uint4 v = *(const uint4*)(&S[nn * 216 + 64 + d8]);
        *(uint4*)(lKt + ((size_t)(b * 512 + n0 + nn) * 128 + d8)) = v;
      }
      #pragma unroll
      for (int it = 0; it < 2; ++it) {
        const int idx = it * 256 + tid;
        const int hq = idx >> 7, dk = (idx >> 3) & 15, n8 = (idx & 7) * 8;
        const int lc = hq * 16 + dk;
        unsigned wr[4];
        #pragma unroll
        for (int j = 0; j < 4; ++j)
          wr[j] = (unsigned)S[(n8 + 2 * j) * 216 + lc] |
                  ((unsigned)S[(n8 + 2 * j + 1) * 216 + lc] << 16);
        uint4 o; o.x = wr[0]; o.y = wr[1]; o.z = wr[2]; o.w = wr[3];
        *(uint4*)(gVt + (((size_t)(b * 8 + 4 + hq) * 16 + dk) * 512 + n0 + n8)) = o;
      }
    }
    __syncthreads();
  }
}

// ---------------------------------------------------------------------------
// decode: block = (b, 16-step window), 8 waves = 8 heads, sorted-node space.
// Phase 0: fused Q. Phase A: QK/online-softmax/PV, prefix skip; l_run via
// ones-MFMA (column sums on matrix pipe). Phase C: cvtpk logit stores.
// Write pass: per-wave max-tree log-softmax, single-wave full-row writes.
// ---------------------------------------------------------------------------
__global__ __launch_bounds__(512, 8)
void decode_mfma(const ushortx* __restrict__ gK,
                 const ushortx* __restrict__ gVt,
                 const ushortx* __restrict__ lKt,
                 const float* __restrict__ emb,
                 const int* __restrict__ seq,
                 const ushortx* __restrict__ WsbT,
                 const float* __restrict__ Abuf,
                 const ushortx* __restrict__ Qb0,
                 const ushortx* __restrict__ Ksrt,
                 const ushortx* __restrict__ n_orig,
                 float* __restrict__ out) {
  const int id = blockIdx.x;
  const int xcd = id & 7, pos = id >> 3;
  const int b = xcd * 16 + (pos >> 5);
  const int s0 = (pos & 31) * 16;
  const int tid = threadIdx.x;
  const int w = tid >> 6, l = tid & 63;
  const int m16 = l & 15, lg = l >> 4;

  __shared__ ushortx logitsTb[512 * 26];        // bf16 [p][s], stride 26
  __shared__ ushortx ctxh[16][136];             // ctx staging -> heads later
  __shared__ ushortx Qt[16][136];
  __shared__ ushortx norig_l[512];
  __shared__ ushortx Ko[16];
  __shared__ int sel_l[16];
  __shared__ float Ab[128];

  norig_l[tid] = n_orig[b * 512 + tid];
  if (tid < 16) {
    Ko[tid] = Ksrt[b * 512 + s0 + tid];
    const int sg = s0 + tid;
    sel_l[tid] = (sg >= 1) ? seq[b * 512 + sg - 1] : 0;
  }
  if (tid < 128) Ab[tid] = Abuf[b * 128 + tid];
  __syncthreads();

  // ---- phase 0a: stage 16 ctx rows (bf16), 256 threads ----
  if (tid < 256) {
    const int row = tid >> 4, c8 = (tid & 15) * 8;
    const float* er = emb + ((size_t)b * 512 + sel_l[row]) * 128 + c8;
    float4 f0 = *(const float4*)(er);
    float4 f1 = *(const float4*)(er + 4);
    unsigned* dst = (unsigned*)&ctxh[row][c8];
    dst[0] = cvtpk(f0.x, f0.y); dst[1] = cvtpk(f0.z, f0.w);
    dst[2] = cvtpk(f1.x, f1.y); dst[3] = cvtpk(f1.z, f1.w);
  }
  __syncthreads();

  // ---- phase 0b: Q = ctx @ Wsb + Ab (per-wave head tile) ----
  const int h = w;
  {
    s8v aw[4];
    #pragma unroll
    for (int ks = 0; ks < 4; ++ks)
      aw[ks] = *(const s8v*)(WsbT + (size_t)(h * 16 + m16) * 128 + ks * 32 + lg * 8);
    f4v acc = {0.f, 0.f, 0.f, 0.f};
    #pragma unroll
    for (int ks = 0; ks < 4; ++ks) {
      const s8v bf = *(const s8v*)(&ctxh[m16][ks * 32 + lg * 8]);
      acc = MFMA_(aw[ks], bf, acc, 0, 0, 0);
    }
    const int d0 = h * 16 + 4 * lg;
    unsigned q01 = cvtpk(acc[0] + Ab[d0], acc[1] + Ab[d0 + 1]);
    unsigned q23 = cvtpk(acc[2] + Ab[d0 + 2], acc[3] + Ab[d0 + 3]);
    if (s0 == 0 && m16 == 0) {                // step 0 uses precomputed Q
      q01 = *(const unsigned*)(Qb0 + b * 128 + d0);
      q23 = *(const unsigned*)(Qb0 + b * 128 + d0 + 2);
    }
    unsigned* qdst = (unsigned*)&Qt[m16][d0];
    qdst[0] = q01; qdst[1] = q23;
  }
  __syncthreads();

  s8v qf = {};
  if (lg < 2) qf = *(const s8v*)(&Qt[m16][h * 16 + lg * 8]);

  s8v ones;
  {
    union { unsigned u[4]; s8v v; } ou;
    ou.u[0] = 0x3F803F80u; ou.u[1] = 0x3F803F80u;
    ou.u[2] = 0x3F803F80u; ou.u[3] = 0x3F803F80u;
    ones = ou.v;
  }

  const int K0i = (int)Ko[0], K15 = (int)Ko[15];
  const int chStart = K0i >> 5;
  const int chClean = (K15 + 31) >> 5;
  const int Ks = (int)Ko[m16];
  const size_t bh = (size_t)(b * 8 + h);

  f4v Oacc = {0.f, 0.f, 0.f, 0.f};
  f4v Lacc = {0.f, 0.f, 0.f, 0.f};              // col-sums of P (rows equal)
  float m_run = NEG_BIG_;
  const int nA0 = 8 * (m16 >> 2) + (m16 & 3);

  for (int ch = chStart; ch < 16; ++ch) {
    const int base = ch * 32;
    s8v a0 = {}, a1 = {};
    if (lg < 2) {
      a0 = *(const s8v*)(gK + ((bh * 512 + base + nA0) * 16 + lg * 8));
      a1 = *(const s8v*)(gK + ((bh * 512 + base + nA0 + 4) * 16 + lg * 8));
    }
    const s8v av = *(const s8v*)(gVt + ((bh * 16 + m16) * 512 + base + lg * 8));

    f4v z = {0.f, 0.f, 0.f, 0.f};
    f4v st0 = MFMA_(a0, qf, z, 0, 0, 0);
    f4v st1 = MFMA_(a1, qf, z, 0, 0, 0);

    float cm = max3f(st0[0], st0[1], st0[2]);
    cm = max3f(cm, st0[3], st1[0]);
    cm = max3f(cm, st1[1], st1[2]);
    cm = fmaxf(cm, st1[3]);
    cm = fmaxf(cm, __shfl_xor(cm, 16));
    cm = fmaxf(cm, __shfl_xor(cm, 32));

    if (__any(cm > m_run + 8.0f)) {
      const float mn = fmaxf(m_run, cm);
      const float cr = exp2_hw(m_run - mn);
      m_run = mn;
      Lacc[0] *= cr;
      Oacc[0] *= cr; Oacc[1] *= cr; Oacc[2] *= cr; Oacc[3] *= cr;
    }

    float p[8];
    #pragma unroll
    for (int r = 0; r < 4; ++r) {
      p[r]     = exp2_hw(st0[r] - m_run);
      p[4 + r] = exp2_hw(st1[r] - m_run);
    }
    if (ch < chClean) {
      const int nb = base + 8 * lg;
      #pragma unroll
      for (int j = 0; j < 8; ++j) p[j] = (nb + j < Ks) ? 0.f : p[j];
    }
    union { unsigned u[4]; s8v v; } pu;
    pu.u[0] = cvtpk(p[0], p[1]); pu.u[1] = cvtpk(p[2], p[3]);
    pu.u[2] = cvtpk(p[4], p[5]); pu.u[3] = cvtpk(p[6], p[7]);
    Oacc = MFMA_(av, pu.v, Oacc, 0, 0, 0);
    Lacc = MFMA_(ones, pu.v, Lacc, 0, 0, 0);
  }

  const float scale = rcp_hw(Lacc[0]) * HSC_;   // Lacc[0] = full column sum
  {
    const int d0 = h * 16 + 4 * lg;
    unsigned* hd = (unsigned*)&ctxh[m16][d0];   // reuse ctxh as heads
    hd[0] = cvtpk(Oacc[0] * scale, Oacc[1] * scale);
    hd[1] = cvtpk(Oacc[2] * scale, Oacc[3] * scale);
  }
  __syncthreads();

  // ---- phase C: logits^T[p][s] = mfma(lKt rows, heads cols), prefix skip ----
  #pragma unroll
  for (int nt = 0; nt < 4; ++nt) {
    const int n0 = w * 64 + nt * 16;
    const int pb = (n0 + 4 * lg) * 26 + m16;
    if (n0 + 16 <= K0i) {                       // fully masked tile
      logitsTb[pb]      = f2bf(MASKC_);
      logitsTb[pb + 26] = f2bf(MASKC_);
      logitsTb[pb + 52] = f2bf(MASKC_);
      logitsTb[pb + 78] = f2bf(MASKC_);
      continue;
    }
    f4v acc = {0.f, 0.f, 0.f, 0.f};
    #pragma unroll
    for (int ks = 0; ks < 4; ++ks) {
      const s8v aL = *(const s8v*)(lKt + ((size_t)b * 512 + n0 + m16) * 128 + ks * 32 + lg * 8);
      const s8v bH = *(const s8v*)(&ctxh[m16][ks * 32 + lg * 8]);
      acc = MFMA_(aL, bH, acc, 0, 0, 0);
    }
    const bool bnd = (n0 < K15);
    float lgv[4];
    #pragma unroll
    for (int r = 0; r < 4; ++r) {
      const int p = n0 + 4 * lg + r;
      float x = fminf(fmaxf(acc[r], -43.f), 43.f);   // = 2*log2e*real_x
      const float e2 = exp2_hw(x);
      float lv = CLIP_ * (e2 - 1.f) * rcp_hw(e2 + 1.f);
      if (bnd && p < Ks) lv = MASKC_;
      lgv[r] = lv;
    }
    const unsigned pk01 = cvtpk(lgv[0], lgv[1]);
    const unsigned pk23 = cvtpk(lgv[2], lgv[3]);
    logitsTb[pb]      = (ushortx)pk01;
    logitsTb[pb + 26] = (ushortx)(pk01 >> 16);
    logitsTb[pb + 52] = (ushortx)pk23;
    logitsTb[pb + 78] = (ushortx)(pk23 >> 16);
  }
  __syncthreads();

  // ---- log_softmax over p per step; single-wave full-row writes ----
  int no[8];
  #pragma unroll
  for (int i = 0; i < 8; ++i) no[i] = (int)norig_l[i * 64 + l];
  #pragma unroll
  for (int pass = 0; pass < 2; ++pass) {
    const int s = w + pass * 8;
    float v[8];
    #pragma unroll
    for (int i = 0; i < 8; ++i) v[i] = bf2f(logitsTb[(i * 64 + l) * 26 + s]);
    float mm = max3f(v[0], v[1], v[2]);
    mm = max3f(mm, v[3], v[4]);
    mm = max3f(mm, v[5], v[6]);
    mm = fmaxf(mm, v[7]);
    #pragma unroll
    for (int off = 1; off <= 32; off <<= 1) mm = fmaxf(mm, __shfl_xor(mm, off));
    float es = 0.f;
    #pragma unroll
    for (int i = 0; i < 8; ++i) es += exp2_hw((v[i] - mm) * L2E_);
    #pragma unroll
    for (int off = 1; off <= 32; off <<= 1) es += __shfl_xor(es, off);
    const float logZ = mm + LN2_ * log2_hw(es);
    float* orow = out + ((size_t)(b * N_ + s0 + s)) * N_;
    #pragma unroll
    for (int i = 0; i < 8; ++i)
      orow[no[i]] = fmaxf(v[i] - logZ, NEG_BIG_);
  }
}

// ---------------------------------------------------------------------------
extern "C" void kernel_launch(void* const* d_in, const int* in_sizes, int n_in,
                              void* d_out, int out_size, void* d_ws, size_t ws_size,
                              hipStream_t stream) {
  const float* emb   = (const float*)d_in[0];
  const int*   seq   = (const int*)d_in[1];
  const float* Wp    = (const float*)d_in[2];
  const float* Wnode = (const float*)d_in[3];
  const float* Wfix  = (const float*)d_in[4];
  const float* Wstep = (const float*)d_in[5];
  const float* Wout  = (const float*)d_in[6];
  float* out = (float*)d_out;

  ushortx* gK    = (ushortx*)d_ws;                       // 8388608 u16
  ushortx* gVt   = gK   + (size_t)8388608;               // 8388608 u16
  ushortx* lKt   = gVt  + (size_t)8388608;               // 8388608 u16
  ushortx* WfT   = lKt  + (size_t)8388608;               //   49152 u16
  ushortx* WsbT  = WfT  + (size_t)49152;                 //   16384 u16
  ushortx* Ksrt  = WsbT + (size_t)16384;                 //   65536 u16
  ushortx* n_or  = Ksrt + (size_t)65536;                 //   65536 u16
  ushortx* Qb0   = n_or + (size_t)65536;                 //   16384 u16
  float*   Abuf  = (float*)(Qb0 + (size_t)16384);        //   16384 f32

  const long long lp_elems = (long long)B_ * N_ * N_;
  const int tail = (int)((long long)out_size - lp_elems);

  prologue<<<512, 512, 0, stream>>>(emb, seq, Wp, Wnode, Wfix, Wstep, Wout,
                                    WfT, WsbT, Ksrt, n_or, Qb0, Abuf,
                                    out, tail > 0 ? tail : 0);
  proj_mfma<<<1024, 256, 0, stream>>>(emb, WfT, n_or, gK, gVt, lKt);
  decode_mfma<<<4096, 512, 0, stream>>>(gK, gVt, lKt, emb, seq, WsbT, Abuf,
                                        Qb0, Ksrt, n_or, out);
}

// Round 13
// 238.016 us; speedup vs baseline: 1.1022x; 1.0010x over previous
//
#include <hip/hip_runtime.h>
#include <math.h>

#define B_ 128
#define N_ 512
#define D_ 128
#define H_ 8
#define NORM_ 11.313708498984761f
#define SC_ 16.322324f            /* NORM * log2(e) */
#define HSC_ 32.644648f           /* NORM * 2 * log2(e) */
#define CLIP_ 10.0f
#define MASKC_ -3.0e38f
#define NEG_BIG_ -1.0e30f
#define L2E_ 1.4426950408889634f
#define LN2_ 0.6931471805599453f

typedef unsigned short ushortx;
typedef __attribute__((ext_vector_type(8))) short s8v;   // 8 bf16 = 4 VGPR
typedef __attribute__((ext_vector_type(4))) float f4v;   // mfma C/D

#define MFMA_ __builtin_amdgcn_mfma_f32_16x16x32_bf16

__device__ __forceinline__ unsigned short f2bf(float x) {
  union { float f; unsigned u; } v; v.f = x;
  unsigned r = v.u + 0x7fffu + ((v.u >> 16) & 1u);
  return (unsigned short)(r >> 16);
}
__device__ __forceinline__ float bf2f(ushortx u) {
  union { unsigned u; float f; } v; v.u = ((unsigned)u) << 16; return v.f;
}
__device__ __forceinline__ unsigned cvtpk(float lo, float hi) {
  unsigned r;
  asm("v_cvt_pk_bf16_f32 %0, %1, %2" : "=v"(r) : "v"(lo), "v"(hi));
  return r;
}
__device__ __forceinline__ float exp2_hw(float x) {
  float r; asm("v_exp_f32 %0, %1" : "=v"(r) : "v"(x)); return r;
}
__device__ __forceinline__ float log2_hw(float x) {
  float r; asm("v_log_f32 %0, %1" : "=v"(r) : "v"(x)); return r;
}
__device__ __forceinline__ float rcp_hw(float x) {
  float r; asm("v_rcp_f32 %0, %1" : "=v"(r) : "v"(x)); return r;
}
__device__ __forceinline__ float max3f(float a, float b, float c) {
  float r; asm("v_max3_f32 %0, %1, %2, %3" : "=v"(r) : "v"(a), "v"(b), "v"(c));
  return r;
}

// ---------------------------------------------------------------------------
// prologue: 512 blocks x 512 thr, four independent regions by blockIdx:
//   [0,128):   wfold  -> WfT (bf16 WfoldT; cols 256+ have W_out folded), WsbT
//   [128,256): sortperm -> Ksrt, n_orig (LDS atomicMin first-selection table)
//   [256,384): prep -> Qb0, Abuf
//   [384,512): tail -> out[lp..] = float(seq)
// ---------------------------------------------------------------------------
__global__ __launch_bounds__(512)
void prologue(const float* __restrict__ emb, const int* __restrict__ seq,
              const float* __restrict__ Wp, const float* __restrict__ Wnode,
              const float* __restrict__ Wfix, const float* __restrict__ Wstep,
              const float* __restrict__ Wout,
              ushortx* __restrict__ WfT, ushortx* __restrict__ WsbT,
              ushortx* __restrict__ Ksrt, ushortx* __restrict__ n_orig,
              ushortx* __restrict__ Qb0, float* __restrict__ Abuf,
              float* __restrict__ out, int tail_count) {
  const int blk = blockIdx.x;
  const int t = threadIdx.x;

  if (blk < 128) {
    // ---- wfold ----
    const int c = blk * 4 + (t >> 7);
    const int k = t & 127;
    if (c < 256) {
      WfT[c * 128 + k] = f2bf(Wnode[k * 384 + c]);
    } else if (c < 384) {
      const int d = c - 256;
      float s = 0.f;
      #pragma unroll 4
      for (int j = 0; j < 128; ++j) s += Wnode[k * 384 + 256 + j] * Wout[d * 128 + j];
      WfT[c * 128 + k] = f2bf(s);
    } else {
      const int d = c - 384;
      WsbT[d * 128 + k] = f2bf(Wstep[(128 + k) * 128 + d] * SC_);
    }
    return;
  }

  if (blk < 256) {
    // ---- sortperm ----
    const int b = blk - 128;
    const int lane = t & 63, wv = t >> 6;
    __shared__ int Tl[512];
    __shared__ int wsum[8];
    __shared__ int tot_s;

    Tl[t] = 0x7fffffff;
    __syncthreads();
    const int node = seq[b * 512 + t];
    atomicMin(&Tl[node], t + 1);
    __syncthreads();

    const int f = (Tl[node] == t + 1) ? 1 : 0;
    const unsigned long long bal = __ballot(f);
    const int excl = __popcll(bal & ((1ull << lane) - 1ull));
    if (lane == 0) wsum[wv] = __popcll(bal);
    __syncthreads();
    int woff = 0;
    #pragma unroll
    for (int i = 0; i < 8; ++i) woff += (i < wv) ? wsum[i] : 0;
    const int Kt = woff + excl;
    Ksrt[b * 512 + t] = (ushortx)Kt;
    if (f) n_orig[b * 512 + Kt] = (ushortx)node;
    if (t == 511) tot_s = Kt + f;

    const int g = (Tl[t] == 0x7fffffff) ? 1 : 0;
    const unsigned long long bal2 = __ballot(g);
    const int excl2 = __popcll(bal2 & ((1ull << lane) - 1ull));
    const int w2 = __popcll(bal2);
    __syncthreads();
    if (lane == 0) wsum[wv] = w2;
    __syncthreads();
    int woff2 = 0;
    #pragma unroll
    for (int i = 0; i < 8; ++i) woff2 += (i < wv) ? wsum[i] : 0;
    if (g) n_orig[b * 512 + tot_s + woff2 + excl2] = (ushortx)t;
    return;
  }

  if (blk < 384) {
    // ---- prep ----
    const int b = blk - 256;
    __shared__ float4 red4[16][33];
    __shared__ float mean[128];
    const int row0 = t >> 5, c4 = t & 31;
    const float* eb = emb + (size_t)b * 512 * 128;
    float4 acc = {0.f, 0.f, 0.f, 0.f};
    for (int it = 0; it < 32; ++it) {
      const float4 x = *(const float4*)(eb + (size_t)(it * 16 + row0) * 128 + c4 * 4);
      acc.x += x.x; acc.y += x.y; acc.z += x.z; acc.w += x.w;
    }
    red4[row0][c4] = acc;
    __syncthreads();
    if (t < 128) {
      const int c4b = t >> 2, j = t & 3;
      float s = 0.f;
      #pragma unroll
      for (int r = 0; r < 16; ++r) s += ((const float*)&red4[r][c4b])[j];
      mean[t] = s * (1.f / 512.f);
    }
    __syncthreads();
    if (t < 128) {
      float fx = 0.f;
      for (int k = 0; k < 128; ++k) fx += mean[k] * Wfix[k * 128 + t];
      float c = 0.f;
      for (int k = 0; k < 256; ++k) c += Wp[k] * Wstep[k * 128 + t];
      const int sel0 = seq[b * N_];
      const float* ef = eb + (size_t)sel0 * 128;
      float a = 0.f;
      for (int k = 0; k < 128; ++k) a += ef[k] * Wstep[k * 128 + t];
      Qb0[b * 128 + t] = f2bf((fx + c) * SC_);
      Abuf[b * 128 + t] = (fx + a) * SC_;
    }
    return;
  }

  // ---- tail: out[lp + i] = float(seq[i]) ----
  {
    const int i = (blk - 384) * 512 + t;
    if (i < tail_count) out[(size_t)B_ * N_ * N_ + i] = (float)seq[i];
  }
}

// ---------------------------------------------------------------------------
// proj_mfma: gathers E rows in sorted order, emits packed decode layouts:
//   gK [b][h][p][16], gVt [b][h][dk][p], lKt [b][p][128]   (p = sorted node)
// ---------------------------------------------------------------------------
__global__ __launch_bounds__(256)
void proj_mfma(const float* __restrict__ E, const ushortx* __restrict__ WfT,
               const ushortx* __restrict__ n_orig,
               ushortx* __restrict__ gK, ushortx* __restrict__ gVt,
               ushortx* __restrict__ lKt) {
  __shared__ ushortx S[64 * 216];
  const int tid = threadIdx.x;
  const int w = tid >> 6, l = tid & 63;
  const int m16 = l & 15, lg = l >> 4;
  const int b = blockIdx.x >> 3;
  const int n0 = (blockIdx.x & 7) * 64;
  const int p_row = n0 + w * 16 + m16;
  const int orig = (int)n_orig[b * 512 + p_row];
  const float* er = E + ((size_t)b * 512 + orig) * 128;

  s8v af[4];
  #pragma unroll
  for (int ks = 0; ks < 4; ++ks) {
    float4 f0 = *(const float4*)(er + ks * 32 + lg * 8);
    float4 f1 = *(const float4*)(er + ks * 32 + lg * 8 + 4);
    union { unsigned u[4]; s8v v; } au;
    au.u[0] = cvtpk(f0.x, f0.y); au.u[1] = cvtpk(f0.z, f0.w);
    au.u[2] = cvtpk(f1.x, f1.y); au.u[3] = cvtpk(f1.z, f1.w);
    af[ks] = au.v;
  }

  const int lrow = w * 16 + 4 * lg;
  #pragma unroll
  for (int half = 0; half < 2; ++half) {
    const int cb = half * 192;
    #pragma unroll
    for (int ct = 0; ct < 12; ++ct) {
      const int lc = ct * 16 + m16;
      f4v acc = {0.f, 0.f, 0.f, 0.f};
      #pragma unroll
      for (int ks = 0; ks < 4; ++ks) {
        const s8v bf = *(const s8v*)(WfT + (size_t)(cb + lc) * 128 + ks * 32 + lg * 8);
        acc = MFMA_(af[ks], bf, acc, 0, 0, 0);
      }
      const unsigned w01 = cvtpk(acc[0], acc[1]);
      const unsigned w23 = cvtpk(acc[2], acc[3]);
      S[(lrow + 0) * 216 + lc] = (ushortx)(w01 & 0xffffu);
      S[(lrow + 1) * 216 + lc] = (ushortx)(w01 >> 16);
      S[(lrow + 2) * 216 + lc] = (ushortx)(w23 & 0xffffu);
      S[(lrow + 3) * 216 + lc] = (ushortx)(w23 >> 16);
    }
    __syncthreads();

    if (half == 0) {
      #pragma unroll
      for (int it = 0; it < 4; ++it) {
        const int idx = it * 256 + tid;
        const int hh = idx >> 7, nn = (idx >> 1) & 63, hf = idx & 1;
        const uint4 v = *(const uint4*)(&S[nn * 216 + hh * 16 + hf * 8]);
        *(uint4*)(gK + (((size_t)(b * 8 + hh) * 512 + n0 + nn) * 16 + hf * 8)) = v;
      }
      #pragma unroll
      for (int it = 0; it < 2; ++it) {
        const int idx = it * 256 + tid;
        const int hh = idx >> 7, dk = (idx >> 3) & 15, n8 = (idx & 7) * 8;
        const int lc = 128 + hh * 16 + dk;
        unsigned wr[4];
        #pragma unroll
        for (int j = 0; j < 4; ++j)
          wr[j] = (unsigned)S[(n8 + 2 * j) * 216 + lc] |
                  ((unsigned)S[(n8 + 2 * j + 1) * 216 + lc] << 16);
        uint4 o; o.x = wr[0]; o.y = wr[1]; o.z = wr[2]; o.w = wr[3];
        *(uint4*)(gVt + (((size_t)(b * 8 + hh) * 16 + dk) * 512 + n0 + n8)) = o;
      }
    } else {
      #pragma unroll
      for (int it = 0; it < 4; ++it) {
        const int idx = it * 256 + tid;
        const int nn = idx >> 4, d8 = (idx & 15) * 8;
        const uint4 v = *(const uint4*)(&S[nn * 216 + 64 + d8]);
        *(uint4*)(lKt + ((size_t)(b * 512 + n0 + nn) * 128 + d8)) = v;
      }
      #pragma unroll
      for (int it = 0; it < 2; ++it) {
        const int idx = it * 256 + tid;
        const int hq = idx >> 7, dk = (idx >> 3) & 15, n8 = (idx & 7) * 8;
        const int lc = hq * 16 + dk;
        unsigned wr[4];
        #pragma unroll
        for (int j = 0; j < 4; ++j)
          wr[j] = (unsigned)S[(n8 + 2 * j) * 216 + lc] |
                  ((unsigned)S[(n8 + 2 * j + 1) * 216 + lc] << 16);
        uint4 o; o.x = wr[0]; o.y = wr[1]; o.z = wr[2]; o.w = wr[3];
        *(uint4*)(gVt + (((size_t)(b * 8 + 4 + hq) * 16 + dk) * 512 + n0 + n8)) = o;
      }
    }
    __syncthreads();
  }
}

// ---------------------------------------------------------------------------
// decode: block = (b, 16-step window), 8 waves = 8 heads, sorted-node space.
// Phase 0: fused Q. Phase A: QK/online-softmax/PV, prefix skip, depth-1
// software-pipelined operand loads (prefetch ch+1 while computing ch);
// l_run via ones-MFMA. Phase C: cvtpk logit stores.
// Write pass: per-wave max-tree log-softmax, single-wave full-row writes.
// ---------------------------------------------------------------------------
__global__ __launch_bounds__(512, 8)
void decode_mfma(const ushortx* __restrict__ gK,
                 const ushortx* __restrict__ gVt,
                 const ushortx* __restrict__ lKt,
                 const float* __restrict__ emb,
                 const int* __restrict__ seq,
                 const ushortx* __restrict__ WsbT,
                 const float* __restrict__ Abuf,
                 const ushortx* __restrict__ Qb0,
                 const ushortx* __restrict__ Ksrt,
                 const ushortx* __restrict__ n_orig,
                 float* __restrict__ out) {
  const int id = blockIdx.x;
  const int xcd = id & 7, pos = id >> 3;
  const int b = xcd * 16 + (pos >> 5);
  const int s0 = (pos & 31) * 16;
  const int tid = threadIdx.x;
  const int w = tid >> 6, l = tid & 63;
  const int m16 = l & 15, lg = l >> 4;

  __shared__ ushortx logitsTb[512 * 26];        // bf16 [p][s], stride 26
  __shared__ ushortx ctxh[16][136];             // ctx staging -> heads later
  __shared__ ushortx Qt[16][136];
  __shared__ ushortx norig_l[512];
  __shared__ ushortx Ko[16];
  __shared__ int sel_l[16];
  __shared__ float Ab[128];

  norig_l[tid] = n_orig[b * 512 + tid];
  if (tid < 16) {
    Ko[tid] = Ksrt[b * 512 + s0 + tid];
    const int sg = s0 + tid;
    sel_l[tid] = (sg >= 1) ? seq[b * 512 + sg - 1] : 0;
  }
  if (tid < 128) Ab[tid] = Abuf[b * 128 + tid];
  __syncthreads();

  // ---- phase 0a: stage 16 ctx rows (bf16), 256 threads ----
  if (tid < 256) {
    const int row = tid >> 4, c8 = (tid & 15) * 8;
    const float* er = emb + ((size_t)b * 512 + sel_l[row]) * 128 + c8;
    float4 f0 = *(const float4*)(er);
    float4 f1 = *(const float4*)(er + 4);
    unsigned* dst = (unsigned*)&ctxh[row][c8];
    dst[0] = cvtpk(f0.x, f0.y); dst[1] = cvtpk(f0.z, f0.w);
    dst[2] = cvtpk(f1.x, f1.y); dst[3] = cvtpk(f1.z, f1.w);
  }
  __syncthreads();

  // ---- phase 0b: Q = ctx @ Wsb + Ab (per-wave head tile) ----
  const int h = w;
  {
    s8v aw[4];
    #pragma unroll
    for (int ks = 0; ks < 4; ++ks)
      aw[ks] = *(const s8v*)(WsbT + (size_t)(h * 16 + m16) * 128 + ks * 32 + lg * 8);
    f4v acc = {0.f, 0.f, 0.f, 0.f};
    #pragma unroll
    for (int ks = 0; ks < 4; ++ks) {
      const s8v bf = *(const s8v*)(&ctxh[m16][ks * 32 + lg * 8]);
      acc = MFMA_(aw[ks], bf, acc, 0, 0, 0);
    }
    const int d0 = h * 16 + 4 * lg;
    unsigned q01 = cvtpk(acc[0] + Ab[d0], acc[1] + Ab[d0 + 1]);
    unsigned q23 = cvtpk(acc[2] + Ab[d0 + 2], acc[3] + Ab[d0 + 3]);
    if (s0 == 0 && m16 == 0) {                // step 0 uses precomputed Q
      q01 = *(const unsigned*)(Qb0 + b * 128 + d0);
      q23 = *(const unsigned*)(Qb0 + b * 128 + d0 + 2);
    }
    unsigned* qdst = (unsigned*)&Qt[m16][d0];
    qdst[0] = q01; qdst[1] = q23;
  }
  __syncthreads();

  s8v qf = {};
  if (lg < 2) qf = *(const s8v*)(&Qt[m16][h * 16 + lg * 8]);

  s8v ones;
  {
    union { unsigned u[4]; s8v v; } ou;
    ou.u[0] = 0x3F803F80u; ou.u[1] = 0x3F803F80u;
    ou.u[2] = 0x3F803F80u; ou.u[3] = 0x3F803F80u;
    ones = ou.v;
  }

  const int K0i = (int)Ko[0], K15 = (int)Ko[15];
  const int chStart = K0i >> 5;
  const int chClean = (K15 + 31) >> 5;
  const int Ks = (int)Ko[m16];
  const size_t bh = (size_t)(b * 8 + h);

  f4v Oacc = {0.f, 0.f, 0.f, 0.f};
  f4v Lacc = {0.f, 0.f, 0.f, 0.f};              // col-sums of P (rows equal)
  float m_run = NEG_BIG_;
  const int nA0 = 8 * (m16 >> 2) + (m16 & 3);

  // ---- depth-1 software pipeline: prefetch ch+1 operands during ch compute
  s8v a0 = {}, a1 = {}, av;
  {
    const int base = chStart * 32;
    if (lg < 2) {
      a0 = *(const s8v*)(gK + ((bh * 512 + base + nA0) * 16 + lg * 8));
      a1 = *(const s8v*)(gK + ((bh * 512 + base + nA0 + 4) * 16 + lg * 8));
    }
    av = *(const s8v*)(gVt + ((bh * 16 + m16) * 512 + base + lg * 8));
  }

  for (int ch = chStart; ch < 16; ++ch) {
    s8v na0 = {}, na1 = {}, nav = {};
    if (ch + 1 < 16) {
      const int nbase = (ch + 1) * 32;
      if (lg < 2) {
        na0 = *(const s8v*)(gK + ((bh * 512 + nbase + nA0) * 16 + lg * 8));
        na1 = *(const s8v*)(gK + ((bh * 512 + nbase + nA0 + 4) * 16 + lg * 8));
      }
      nav = *(const s8v*)(gVt + ((bh * 16 + m16) * 512 + nbase + lg * 8));
    }

    const int base = ch * 32;
    f4v z = {0.f, 0.f, 0.f, 0.f};
    f4v st0 = MFMA_(a0, qf, z, 0, 0, 0);
    f4v st1 = MFMA_(a1, qf, z, 0, 0, 0);

    float cm = max3f(st0[0], st0[1], st0[2]);
    cm = max3f(cm, st0[3], st1[0]);
    cm = max3f(cm, st1[1], st1[2]);
    cm = fmaxf(cm, st1[3]);
    cm = fmaxf(cm, __shfl_xor(cm, 16));
    cm = fmaxf(cm, __shfl_xor(cm, 32));

    if (__any(cm > m_run + 8.0f)) {
      const float mn = fmaxf(m_run, cm);
      const float cr = exp2_hw(m_run - mn);
      m_run = mn;
      Lacc[0] *= cr;
      Oacc[0] *= cr; Oacc[1] *= cr; Oacc[2] *= cr; Oacc[3] *= cr;
    }

    float p[8];
    #pragma unroll
    for (int r = 0; r < 4; ++r) {
      p[r]     = exp2_hw(st0[r] - m_run);
      p[4 + r] = exp2_hw(st1[r] - m_run);
    }
    if (ch < chClean) {
      const int nb = base + 8 * lg;
      #pragma unroll
      for (int j = 0; j < 8; ++j) p[j] = (nb + j < Ks) ? 0.f : p[j];
    }
    union { unsigned u[4]; s8v v; } pu;
    pu.u[0] = cvtpk(p[0], p[1]); pu.u[1] = cvtpk(p[2], p[3]);
    pu.u[2] = cvtpk(p[4], p[5]); pu.u[3] = cvtpk(p[6], p[7]);
    Oacc = MFMA_(av, pu.v, Oacc, 0, 0, 0);
    Lacc = MFMA_(ones, pu.v, Lacc, 0, 0, 0);

    a0 = na0; a1 = na1; av = nav;
  }

  const float scale = rcp_hw(Lacc[0]) * HSC_;   // Lacc[0] = full column sum
  {
    const int d0 = h * 16 + 4 * lg;
    unsigned* hd = (unsigned*)&ctxh[m16][d0];   // reuse ctxh as heads
    hd[0] = cvtpk(Oacc[0] * scale, Oacc[1] * scale);
    hd[1] = cvtpk(Oacc[2] * scale, Oacc[3] * scale);
  }
  __syncthreads();

  // ---- phase C: logits^T[p][s] = mfma(lKt rows, heads cols), prefix skip ----
  #pragma unroll
  for (int nt = 0; nt < 4; ++nt) {
    const int n0 = w * 64 + nt * 16;
    const int pb = (n0 + 4 * lg) * 26 + m16;
    if (n0 + 16 <= K0i) {                       // fully masked tile
      logitsTb[pb]      = f2bf(MASKC_);
      logitsTb[pb + 26] = f2bf(MASKC_);
      logitsTb[pb + 52] = f2bf(MASKC_);
      logitsTb[pb + 78] = f2bf(MASKC_);
      continue;
    }
    f4v acc = {0.f, 0.f, 0.f, 0.f};
    #pragma unroll
    for (int ks = 0; ks < 4; ++ks) {
      const s8v aL = *(const s8v*)(lKt + ((size_t)b * 512 + n0 + m16) * 128 + ks * 32 + lg * 8);
      const s8v bH = *(const s8v*)(&ctxh[m16][ks * 32 + lg * 8]);
      acc = MFMA_(aL, bH, acc, 0, 0, 0);
    }
    const bool bnd = (n0 < K15);
    float lgv[4];
    #pragma unroll
    for (int r = 0; r < 4; ++r) {
      const int p = n0 + 4 * lg + r;
      float x = fminf(fmaxf(acc[r], -43.f), 43.f);   // = 2*log2e*real_x
      const float e2 = exp2_hw(x);
      float lv = CLIP_ * (e2 - 1.f) * rcp_hw(e2 + 1.f);
      if (bnd && p < Ks) lv = MASKC_;
      lgv[r] = lv;
    }
    const unsigned pk01 = cvtpk(lgv[0], lgv[1]);
    const unsigned pk23 = cvtpk(lgv[2], lgv[3]);
    logitsTb[pb]      = (ushortx)pk01;
    logitsTb[pb + 26] = (ushortx)(pk01 >> 16);
    logitsTb[pb + 52] = (ushortx)pk23;
    logitsTb[pb + 78] = (ushortx)(pk23 >> 16);
  }
  __syncthreads();

  // ---- log_softmax over p per step; single-wave full-row writes ----
  int no[8];
  #pragma unroll
  for (int i = 0; i < 8; ++i) no[i] = (int)norig_l[i * 64 + l];
  #pragma unroll
  for (int pass = 0; pass < 2; ++pass) {
    const int s = w + pass * 8;
    float v[8];
    #pragma unroll
    for (int i = 0; i < 8; ++i) v[i] = bf2f(logitsTb[(i * 64 + l) * 26 + s]);
    float mm = max3f(v[0], v[1], v[2]);
    mm = max3f(mm, v[3], v[4]);
    mm = max3f(mm, v[5], v[6]);
    mm = fmaxf(mm, v[7]);
    #pragma unroll
    for (int off = 1; off <= 32; off <<= 1) mm = fmaxf(mm, __shfl_xor(mm, off));
    float es = 0.f;
    #pragma unroll
    for (int i = 0; i < 8; ++i) es += exp2_hw((v[i] - mm) * L2E_);
    #pragma unroll
    for (int off = 1; off <= 32; off <<= 1) es += __shfl_xor(es, off);
    const float logZ = mm + LN2_ * log2_hw(es);
    float* orow = out + ((size_t)(b * N_ + s0 + s)) * N_;
    #pragma unroll
    for (int i = 0; i < 8; ++i)
      orow[no[i]] = fmaxf(v[i] - logZ, NEG_BIG_);
  }
}

// ---------------------------------------------------------------------------
extern "C" void kernel_launch(void* const* d_in, const int* in_sizes, int n_in,
                              void* d_out, int out_size, void* d_ws, size_t ws_size,
                              hipStream_t stream) {
  const float* emb   = (const float*)d_in[0];
  const int*   seq   = (const int*)d_in[1];
  const float* Wp    = (const float*)d_in[2];
  const float* Wnode = (const float*)d_in[3];
  const float* Wfix  = (const float*)d_in[4];
  const float* Wstep = (const float*)d_in[5];
  const float* Wout  = (const float*)d_in[6];
  float* out = (float*)d_out;

  ushortx* gK    = (ushortx*)d_ws;                       // 8388608 u16
  ushortx* gVt   = gK   + (size_t)8388608;               // 8388608 u16
  ushortx* lKt   = gVt  + (size_t)8388608;               // 8388608 u16
  ushortx* WfT   = lKt  + (size_t)8388608;               //   49152 u16
  ushortx* WsbT  = WfT  + (size_t)49152;                 //   16384 u16
  ushortx* Ksrt  = WsbT + (size_t)16384;                 //   65536 u16
  ushortx* n_or  = Ksrt + (size_t)65536;                 //   65536 u16
  ushortx* Qb0   = n_or + (size_t)65536;                 //   16384 u16
  float*   Abuf  = (float*)(Qb0 + (size_t)16384);        //   16384 f32

  const long long lp_elems = (long long)B_ * N_ * N_;
  const int tail = (int)((long long)out_size - lp_elems);

  prologue<<<512, 512, 0, stream>>>(emb, seq, Wp, Wnode, Wfix, Wstep, Wout,
                                    WfT, WsbT, Ksrt, n_or, Qb0, Abuf,
                                    out, tail > 0 ? tail : 0);
  proj_mfma<<<1024, 256, 0, stream>>>(emb, WfT, n_or, gK, gVt, lKt);
  decode_mfma<<<4096, 512, 0, stream>>>(gK, gVt, lKt, emb, seq, WsbT, Abuf,
                                        Qb0, Ksrt, n_or, out);
}

// Round 14
// 224.603 us; speedup vs baseline: 1.1680x; 1.0597x over previous
//
#include <hip/hip_runtime.h>
#include <math.h>

#define B_ 128
#define N_ 512
#define D_ 128
#define H_ 8
#define NORM_ 11.313708498984761f
#define SC_ 16.322324f            /* NORM * log2(e) */
#define HSC_ 32.644648f           /* NORM * 2 * log2(e) */
#define CLIP_ 10.0f
#define MASKC_ -3.0e38f
#define NEG_BIG_ -1.0e30f
#define L2E_ 1.4426950408889634f
#define LN2_ 0.6931471805599453f

typedef unsigned short ushortx;
typedef __attribute__((ext_vector_type(8))) short s8v;   // 8 bf16 = 4 VGPR
typedef __attribute__((ext_vector_type(4))) float f4v;   // mfma C/D

#define MFMA_ __builtin_amdgcn_mfma_f32_16x16x32_bf16

__device__ __forceinline__ unsigned short f2bf(float x) {
  union { float f; unsigned u; } v; v.f = x;
  unsigned r = v.u + 0x7fffu + ((v.u >> 16) & 1u);
  return (unsigned short)(r >> 16);
}
__device__ __forceinline__ float bf2f(ushortx u) {
  union { unsigned u; float f; } v; v.u = ((unsigned)u) << 16; return v.f;
}
__device__ __forceinline__ unsigned cvtpk(float lo, float hi) {
  unsigned r;
  asm("v_cvt_pk_bf16_f32 %0, %1, %2" : "=v"(r) : "v"(lo), "v"(hi));
  return r;
}
__device__ __forceinline__ float exp2_hw(float x) {
  float r; asm("v_exp_f32 %0, %1" : "=v"(r) : "v"(x)); return r;
}
__device__ __forceinline__ float log2_hw(float x) {
  float r; asm("v_log_f32 %0, %1" : "=v"(r) : "v"(x)); return r;
}
__device__ __forceinline__ float rcp_hw(float x) {
  float r; asm("v_rcp_f32 %0, %1" : "=v"(r) : "v"(x)); return r;
}
__device__ __forceinline__ float max3f(float a, float b, float c) {
  float r; asm("v_max3_f32 %0, %1, %2, %3" : "=v"(r) : "v"(a), "v"(b), "v"(c));
  return r;
}

// ---------------------------------------------------------------------------
// prologue: 512 blocks x 512 thr, four independent regions by blockIdx:
//   [0,128):   wfold  -> WfT (bf16 WfoldT; cols 256+ have W_out folded), WsbT
//   [128,256): sortperm -> Ksrt, n_orig (LDS atomicMin first-selection table)
//   [256,384): prep -> Qb0, Abuf
//   [384,512): tail -> out[lp..] = float(seq)
// ---------------------------------------------------------------------------
__global__ __launch_bounds__(512)
void prologue(const float* __restrict__ emb, const int* __restrict__ seq,
              const float* __restrict__ Wp, const float* __restrict__ Wnode,
              const float* __restrict__ Wfix, const float* __restrict__ Wstep,
              const float* __restrict__ Wout,
              ushortx* __restrict__ WfT, ushortx* __restrict__ WsbT,
              ushortx* __restrict__ Ksrt, ushortx* __restrict__ n_orig,
              ushortx* __restrict__ Qb0, float* __restrict__ Abuf,
              float* __restrict__ out, int tail_count) {
  const int blk = blockIdx.x;
  const int t = threadIdx.x;

  if (blk < 128) {
    // ---- wfold ----
    const int c = blk * 4 + (t >> 7);
    const int k = t & 127;
    if (c < 256) {
      WfT[c * 128 + k] = f2bf(Wnode[k * 384 + c]);
    } else if (c < 384) {
      const int d = c - 256;
      float s = 0.f;
      #pragma unroll 4
      for (int j = 0; j < 128; ++j) s += Wnode[k * 384 + 256 + j] * Wout[d * 128 + j];
      WfT[c * 128 + k] = f2bf(s);
    } else {
      const int d = c - 384;
      WsbT[d * 128 + k] = f2bf(Wstep[(128 + k) * 128 + d] * SC_);
    }
    return;
  }

  if (blk < 256) {
    // ---- sortperm ----
    const int b = blk - 128;
    const int lane = t & 63, wv = t >> 6;
    __shared__ int Tl[512];
    __shared__ int wsum[8];
    __shared__ int tot_s;

    Tl[t] = 0x7fffffff;
    __syncthreads();
    const int node = seq[b * 512 + t];
    atomicMin(&Tl[node], t + 1);
    __syncthreads();

    const int f = (Tl[node] == t + 1) ? 1 : 0;
    const unsigned long long bal = __ballot(f);
    const int excl = __popcll(bal & ((1ull << lane) - 1ull));
    if (lane == 0) wsum[wv] = __popcll(bal);
    __syncthreads();
    int woff = 0;
    #pragma unroll
    for (int i = 0; i < 8; ++i) woff += (i < wv) ? wsum[i] : 0;
    const int Kt = woff + excl;
    Ksrt[b * 512 + t] = (ushortx)Kt;
    if (f) n_orig[b * 512 + Kt] = (ushortx)node;
    if (t == 511) tot_s = Kt + f;

    const int g = (Tl[t] == 0x7fffffff) ? 1 : 0;
    const unsigned long long bal2 = __ballot(g);
    const int excl2 = __popcll(bal2 & ((1ull << lane) - 1ull));
    const int w2 = __popcll(bal2);
    __syncthreads();
    if (lane == 0) wsum[wv] = w2;
    __syncthreads();
    int woff2 = 0;
    #pragma unroll
    for (int i = 0; i < 8; ++i) woff2 += (i < wv) ? wsum[i] : 0;
    if (g) n_orig[b * 512 + tot_s + woff2 + excl2] = (ushortx)t;
    return;
  }

  if (blk < 384) {
    // ---- prep ----
    const int b = blk - 256;
    __shared__ float4 red4[16][33];
    __shared__ float mean[128];
    const int row0 = t >> 5, c4 = t & 31;
    const float* eb = emb + (size_t)b * 512 * 128;
    float4 acc = {0.f, 0.f, 0.f, 0.f};
    for (int it = 0; it < 32; ++it) {
      const float4 x = *(const float4*)(eb + (size_t)(it * 16 + row0) * 128 + c4 * 4);
      acc.x += x.x; acc.y += x.y; acc.z += x.z; acc.w += x.w;
    }
    red4[row0][c4] = acc;
    __syncthreads();
    if (t < 128) {
      const int c4b = t >> 2, j = t & 3;
      float s = 0.f;
      #pragma unroll
      for (int r = 0; r < 16; ++r) s += ((const float*)&red4[r][c4b])[j];
      mean[t] = s * (1.f / 512.f);
    }
    __syncthreads();
    if (t < 128) {
      float fx = 0.f;
      for (int k = 0; k < 128; ++k) fx += mean[k] * Wfix[k * 128 + t];
      float c = 0.f;
      for (int k = 0; k < 256; ++k) c += Wp[k] * Wstep[k * 128 + t];
      const int sel0 = seq[b * N_];
      const float* ef = eb + (size_t)sel0 * 128;
      float a = 0.f;
      for (int k = 0; k < 128; ++k) a += ef[k] * Wstep[k * 128 + t];
      Qb0[b * 128 + t] = f2bf((fx + c) * SC_);
      Abuf[b * 128 + t] = (fx + a) * SC_;
    }
    return;
  }

  // ---- tail: out[lp + i] = float(seq[i]) ----
  {
    const int i = (blk - 384) * 512 + t;
    if (i < tail_count) out[(size_t)B_ * N_ * N_ + i] = (float)seq[i];
  }
}

// ---------------------------------------------------------------------------
// proj_mfma: gathers E rows in sorted order, emits packed decode layouts:
//   gK [b][h][p][16], gVt [b][h][dk][p], lKt [b][p][128]   (p = sorted node)
// ---------------------------------------------------------------------------
__global__ __launch_bounds__(256)
void proj_mfma(const float* __restrict__ E, const ushortx* __restrict__ WfT,
               const ushortx* __restrict__ n_orig,
               ushortx* __restrict__ gK, ushortx* __restrict__ gVt,
               ushortx* __restrict__ lKt) {
  __shared__ ushortx S[64 * 216];
  const int tid = threadIdx.x;
  const int w = tid >> 6, l = tid & 63;
  const int m16 = l & 15, lg = l >> 4;
  const int b = blockIdx.x >> 3;
  const int n0 = (blockIdx.x & 7) * 64;
  const int p_row = n0 + w * 16 + m16;
  const int orig = (int)n_orig[b * 512 + p_row];
  const float* er = E + ((size_t)b * 512 + orig) * 128;

  s8v af[4];
  #pragma unroll
  for (int ks = 0; ks < 4; ++ks) {
    float4 f0 = *(const float4*)(er + ks * 32 + lg * 8);
    float4 f1 = *(const float4*)(er + ks * 32 + lg * 8 + 4);
    union { unsigned u[4]; s8v v; } au;
    au.u[0] = cvtpk(f0.x, f0.y); au.u[1] = cvtpk(f0.z, f0.w);
    au.u[2] = cvtpk(f1.x, f1.y); au.u[3] = cvtpk(f1.z, f1.w);
    af[ks] = au.v;
  }

  const int lrow = w * 16 + 4 * lg;
  #pragma unroll
  for (int half = 0; half < 2; ++half) {
    const int cb = half * 192;
    #pragma unroll
    for (int ct = 0; ct < 12; ++ct) {
      const int lc = ct * 16 + m16;
      f4v acc = {0.f, 0.f, 0.f, 0.f};
      #pragma unroll
      for (int ks = 0; ks < 4; ++ks) {
        const s8v bf = *(const s8v*)(WfT + (size_t)(cb + lc) * 128 + ks * 32 + lg * 8);
        acc = MFMA_(af[ks], bf, acc, 0, 0, 0);
      }
      const unsigned w01 = cvtpk(acc[0], acc[1]);
      const unsigned w23 = cvtpk(acc[2], acc[3]);
      S[(lrow + 0) * 216 + lc] = (ushortx)(w01 & 0xffffu);
      S[(lrow + 1) * 216 + lc] = (ushortx)(w01 >> 16);
      S[(lrow + 2) * 216 + lc] = (ushortx)(w23 & 0xffffu);
      S[(lrow + 3) * 216 + lc] = (ushortx)(w23 >> 16);
    }
    __syncthreads();

    if (half == 0) {
      #pragma unroll
      for (int it = 0; it < 4; ++it) {
        const int idx = it * 256 + tid;
        const int hh = idx >> 7, nn = (idx >> 1) & 63, hf = idx & 1;
        const uint4 v = *(const uint4*)(&S[nn * 216 + hh * 16 + hf * 8]);
        *(uint4*)(gK + (((size_t)(b * 8 + hh) * 512 + n0 + nn) * 16 + hf * 8)) = v;
      }
      #pragma unroll
      for (int it = 0; it < 2; ++it) {
        const int idx = it * 256 + tid;
        const int hh = idx >> 7, dk = (idx >> 3) & 15, n8 = (idx & 7) * 8;
        const int lc = 128 + hh * 16 + dk;
        unsigned wr[4];
        #pragma unroll
        for (int j = 0; j < 4; ++j)
          wr[j] = (unsigned)S[(n8 + 2 * j) * 216 + lc] |
                  ((unsigned)S[(n8 + 2 * j + 1) * 216 + lc] << 16);
        uint4 o; o.x = wr[0]; o.y = wr[1]; o.z = wr[2]; o.w = wr[3];
        *(uint4*)(gVt + (((size_t)(b * 8 + hh) * 16 + dk) * 512 + n0 + n8)) = o;
      }
    } else {
      #pragma unroll
      for (int it = 0; it < 4; ++it) {
        const int idx = it * 256 + tid;
        const int nn = idx >> 4, d8 = (idx & 15) * 8;
        const uint4 v = *(const uint4*)(&S[nn * 216 + 64 + d8]);
        *(uint4*)(lKt + ((size_t)(b * 512 + n0 + nn) * 128 + d8)) = v;
      }
      #pragma unroll
      for (int it = 0; it < 2; ++it) {
        const int idx = it * 256 + tid;
        const int hq = idx >> 7, dk = (idx >> 3) & 15, n8 = (idx & 7) * 8;
        const int lc = hq * 16 + dk;
        unsigned wr[4];
        #pragma unroll
        for (int j = 0; j < 4; ++j)
          wr[j] = (unsigned)S[(n8 + 2 * j) * 216 + lc] |
                  ((unsigned)S[(n8 + 2 * j + 1) * 216 + lc] << 16);
        uint4 o; o.x = wr[0]; o.y = wr[1]; o.z = wr[2]; o.w = wr[3];
        *(uint4*)(gVt + (((size_t)(b * 8 + 4 + hq) * 16 + dk) * 512 + n0 + n8)) = o;
      }
    }
    __syncthreads();
  }
}

// ---------------------------------------------------------------------------
// decode: block = (b, 32-step window), 8 waves = 8 heads, sorted-node space.
// Phase 0: fused Q for 32 steps. Phase A: dual-state QK/softmax/PV sharing
// one gK/gVt stream (operand traffic per output halved vs 16-step windows).
// Epilogue: r8-proven form x2 halves — bf16 logitsTb LDS, per-wave max-tree
// log-softmax, single-wave full-row writes.
// ---------------------------------------------------------------------------
__global__ __launch_bounds__(512, 8)
void decode_mfma(const ushortx* __restrict__ gK,
                 const ushortx* __restrict__ gVt,
                 const ushortx* __restrict__ lKt,
                 const float* __restrict__ emb,
                 const int* __restrict__ seq,
                 const ushortx* __restrict__ WsbT,
                 const float* __restrict__ Abuf,
                 const ushortx* __restrict__ Qb0,
                 const ushortx* __restrict__ Ksrt,
                 const ushortx* __restrict__ n_orig,
                 float* __restrict__ out) {
  const int id = blockIdx.x;
  const int xcd = id & 7, pos = id >> 3;
  const int b = xcd * 16 + (pos >> 4);
  const int s0 = (pos & 15) * 32;
  const int tid = threadIdx.x;
  const int w = tid >> 6, l = tid & 63;
  const int m16 = l & 15, lg = l >> 4;

  __shared__ ushortx logitsTb[512 * 26];        // bf16 [p][s_local16], stride 26
  __shared__ ushortx ctxh[32][136];             // ctx staging -> heads later
  __shared__ ushortx Qt[32][136];
  __shared__ ushortx norig_l[512];
  __shared__ ushortx Ko[32];
  __shared__ int sel_l[32];
  __shared__ float Ab[128];

  norig_l[tid] = n_orig[b * 512 + tid];
  if (tid < 32) {
    Ko[tid] = Ksrt[b * 512 + s0 + tid];
    const int sg = s0 + tid;
    sel_l[tid] = (sg >= 1) ? seq[b * 512 + sg - 1] : 0;
  }
  if (tid < 128) Ab[tid] = Abuf[b * 128 + tid];
  __syncthreads();

  // ---- phase 0a: stage 32 ctx rows (bf16), 512 threads ----
  {
    const int row = tid >> 4, c8 = (tid & 15) * 8;
    const float* er = emb + ((size_t)b * 512 + sel_l[row]) * 128 + c8;
    float4 f0 = *(const float4*)(er);
    float4 f1 = *(const float4*)(er + 4);
    unsigned* dst = (unsigned*)&ctxh[row][c8];
    dst[0] = cvtpk(f0.x, f0.y); dst[1] = cvtpk(f0.z, f0.w);
    dst[2] = cvtpk(f1.x, f1.y); dst[3] = cvtpk(f1.z, f1.w);
  }
  __syncthreads();

  // ---- phase 0b: Q = ctx @ Wsb + Ab, two 16-step tiles per wave ----
  const int h = w;
  {
    s8v aw[4];
    #pragma unroll
    for (int ks = 0; ks < 4; ++ks)
      aw[ks] = *(const s8v*)(WsbT + (size_t)(h * 16 + m16) * 128 + ks * 32 + lg * 8);
    #pragma unroll
    for (int t = 0; t < 2; ++t) {
      f4v acc = {0.f, 0.f, 0.f, 0.f};
      #pragma unroll
      for (int ks = 0; ks < 4; ++ks) {
        const s8v bf = *(const s8v*)(&ctxh[t * 16 + m16][ks * 32 + lg * 8]);
        acc = MFMA_(aw[ks], bf, acc, 0, 0, 0);
      }
      const int d0 = h * 16 + 4 * lg;
      unsigned q01 = cvtpk(acc[0] + Ab[d0], acc[1] + Ab[d0 + 1]);
      unsigned q23 = cvtpk(acc[2] + Ab[d0 + 2], acc[3] + Ab[d0 + 3]);
      if (s0 == 0 && t == 0 && m16 == 0) {      // step 0 uses precomputed Q
        q01 = *(const unsigned*)(Qb0 + b * 128 + d0);
        q23 = *(const unsigned*)(Qb0 + b * 128 + d0 + 2);
      }
      unsigned* qdst = (unsigned*)&Qt[t * 16 + m16][d0];
      qdst[0] = q01; qdst[1] = q23;
    }
  }
  __syncthreads();

  s8v qfA = {}, qfB = {};
  if (lg < 2) {
    qfA = *(const s8v*)(&Qt[m16][h * 16 + lg * 8]);
    qfB = *(const s8v*)(&Qt[16 + m16][h * 16 + lg * 8]);
  }

  s8v ones;
  {
    union { unsigned u[4]; s8v v; } ou;
    ou.u[0] = 0x3F803F80u; ou.u[1] = 0x3F803F80u;
    ou.u[2] = 0x3F803F80u; ou.u[3] = 0x3F803F80u;
    ones = ou.v;
  }

  const int K0A = (int)Ko[0], K15 = (int)Ko[15];
  const int K0B = (int)Ko[16], K31 = (int)Ko[31];
  const int chStart = K0A >> 5;
  const int chCleanA = (K15 + 31) >> 5;
  const int chCleanB = (K31 + 31) >> 5;
  const int KsA = (int)Ko[m16], KsB = (int)Ko[16 + m16];
  const size_t bh = (size_t)(b * 8 + h);

  f4v OA = {0.f, 0.f, 0.f, 0.f}, OB = {0.f, 0.f, 0.f, 0.f};
  f4v LA = {0.f, 0.f, 0.f, 0.f}, LB = {0.f, 0.f, 0.f, 0.f};
  float mA = NEG_BIG_, mB = NEG_BIG_;
  const int nA0 = 8 * (m16 >> 2) + (m16 & 3);

  for (int ch = chStart; ch < 16; ++ch) {
    const int base = ch * 32;
    s8v a0 = {}, a1 = {};
    if (lg < 2) {
      a0 = *(const s8v*)(gK + ((bh * 512 + base + nA0) * 16 + lg * 8));
      a1 = *(const s8v*)(gK + ((bh * 512 + base + nA0 + 4) * 16 + lg * 8));
    }
    const s8v av = *(const s8v*)(gVt + ((bh * 16 + m16) * 512 + base + lg * 8));
    const int nb = base + 8 * lg;

    f4v z = {0.f, 0.f, 0.f, 0.f};
    {   // half A (steps s0..s0+15)
      f4v st0 = MFMA_(a0, qfA, z, 0, 0, 0);
      f4v st1 = MFMA_(a1, qfA, z, 0, 0, 0);
      float cm = max3f(st0[0], st0[1], st0[2]);
      cm = max3f(cm, st0[3], st1[0]);
      cm = max3f(cm, st1[1], st1[2]);
      cm = fmaxf(cm, st1[3]);
      cm = fmaxf(cm, __shfl_xor(cm, 16));
      cm = fmaxf(cm, __shfl_xor(cm, 32));
      if (__any(cm > mA + 8.0f)) {
        const float mn = fmaxf(mA, cm);
        const float cr = exp2_hw(mA - mn);
        mA = mn;
        LA[0] *= cr;
        OA[0] *= cr; OA[1] *= cr; OA[2] *= cr; OA[3] *= cr;
      }
      float p[8];
      #pragma unroll
      for (int r = 0; r < 4; ++r) {
        p[r]     = exp2_hw(st0[r] - mA);
        p[4 + r] = exp2_hw(st1[r] - mA);
      }
      if (ch < chCleanA) {
        #pragma unroll
        for (int j = 0; j < 8; ++j) p[j] = (nb + j < KsA) ? 0.f : p[j];
      }
      union { unsigned u[4]; s8v v; } pu;
      pu.u[0] = cvtpk(p[0], p[1]); pu.u[1] = cvtpk(p[2], p[3]);
      pu.u[2] = cvtpk(p[4], p[5]); pu.u[3] = cvtpk(p[6], p[7]);
      OA = MFMA_(av, pu.v, OA, 0, 0, 0);
      LA = MFMA_(ones, pu.v, LA, 0, 0, 0);
    }
    {   // half B (steps s0+16..s0+31)
      f4v st0 = MFMA_(a0, qfB, z, 0, 0, 0);
      f4v st1 = MFMA_(a1, qfB, z, 0, 0, 0);
      float cm = max3f(st0[0], st0[1], st0[2]);
      cm = max3f(cm, st0[3], st1[0]);
      cm = max3f(cm, st1[1], st1[2]);
      cm = fmaxf(cm, st1[3]);
      cm = fmaxf(cm, __shfl_xor(cm, 16));
      cm = fmaxf(cm, __shfl_xor(cm, 32));
      if (__any(cm > mB + 8.0f)) {
        const float mn = fmaxf(mB, cm);
        const float cr = exp2_hw(mB - mn);
        mB = mn;
        LB[0] *= cr;
        OB[0] *= cr; OB[1] *= cr; OB[2] *= cr; OB[3] *= cr;
      }
      float p[8];
      #pragma unroll
      for (int r = 0; r < 4; ++r) {
        p[r]     = exp2_hw(st0[r] - mB);
        p[4 + r] = exp2_hw(st1[r] - mB);
      }
      if (ch < chCleanB) {
        #pragma unroll
        for (int j = 0; j < 8; ++j) p[j] = (nb + j < KsB) ? 0.f : p[j];
      }
      union { unsigned u[4]; s8v v; } pu;
      pu.u[0] = cvtpk(p[0], p[1]); pu.u[1] = cvtpk(p[2], p[3]);
      pu.u[2] = cvtpk(p[4], p[5]); pu.u[3] = cvtpk(p[6], p[7]);
      OB = MFMA_(av, pu.v, OB, 0, 0, 0);
      LB = MFMA_(ones, pu.v, LB, 0, 0, 0);
    }
  }

  {
    const float scA = rcp_hw(LA[0]) * HSC_;
    const float scB = rcp_hw(LB[0]) * HSC_;
    const int d0 = h * 16 + 4 * lg;
    unsigned* hdA = (unsigned*)&ctxh[m16][d0];      // heads half A
    hdA[0] = cvtpk(OA[0] * scA, OA[1] * scA);
    hdA[1] = cvtpk(OA[2] * scA, OA[3] * scA);
    unsigned* hdB = (unsigned*)&ctxh[16 + m16][d0]; // heads half B
    hdB[0] = cvtpk(OB[0] * scB, OB[1] * scB);
    hdB[1] = cvtpk(OB[2] * scB, OB[3] * scB);
  }
  __syncthreads();

  // ---- epilogue x2: phase C into logitsTb, then write pass (r8 form) ----
  int no[8];
  #pragma unroll
  for (int i = 0; i < 8; ++i) no[i] = (int)norig_l[i * 64 + l];

  #pragma unroll
  for (int half = 0; half < 2; ++half) {
    const int K0h = half ? K0B : K0A;
    const int K15h = half ? K31 : K15;
    const int Ksh = half ? KsB : KsA;

    #pragma unroll
    for (int nt = 0; nt < 4; ++nt) {
      const int n0 = w * 64 + nt * 16;
      const int pb = (n0 + 4 * lg) * 26 + m16;
      if (n0 + 16 <= K0h) {                     // fully masked tile
        logitsTb[pb]      = f2bf(MASKC_);
        logitsTb[pb + 26] = f2bf(MASKC_);
        logitsTb[pb + 52] = f2bf(MASKC_);
        logitsTb[pb + 78] = f2bf(MASKC_);
        continue;
      }
      f4v acc = {0.f, 0.f, 0.f, 0.f};
      #pragma unroll
      for (int ks = 0; ks < 4; ++ks) {
        const s8v aL = *(const s8v*)(lKt + ((size_t)b * 512 + n0 + m16) * 128 + ks * 32 + lg * 8);
        const s8v bH = *(const s8v*)(&ctxh[half * 16 + m16][ks * 32 + lg * 8]);
        acc = MFMA_(aL, bH, acc, 0, 0, 0);
      }
      const bool bnd = (n0 < K15h);
      float lgv[4];
      #pragma unroll
      for (int r = 0; r < 4; ++r) {
        const int p = n0 + 4 * lg + r;
        float x = fminf(fmaxf(acc[r], -43.f), 43.f);   // = 2*log2e*real_x
        const float e2 = exp2_hw(x);
        float lv = CLIP_ * (e2 - 1.f) * rcp_hw(e2 + 1.f);
        if (bnd && p < Ksh) lv = MASKC_;
        lgv[r] = lv;
      }
      const unsigned pk01 = cvtpk(lgv[0], lgv[1]);
      const unsigned pk23 = cvtpk(lgv[2], lgv[3]);
      logitsTb[pb]      = (ushortx)pk01;
      logitsTb[pb + 26] = (ushortx)(pk01 >> 16);
      logitsTb[pb + 52] = (ushortx)pk23;
      logitsTb[pb + 78] = (ushortx)(pk23 >> 16);
    }
    __syncthreads();

    #pragma unroll
    for (int pass = 0; pass < 2; ++pass) {
      const int s = w + pass * 8;                // local step within half
      float v[8];
      #pragma unroll
      for (int i = 0; i < 8; ++i) v[i] = bf2f(logitsTb[(i * 64 + l) * 26 + s]);
      float mm = max3f(v[0], v[1], v[2]);
      mm = max3f(mm, v[3], v[4]);
      mm = max3f(mm, v[5], v[6]);
      mm = fmaxf(mm, v[7]);
      #pragma unroll
      for (int off = 1; off <= 32; off <<= 1) mm = fmaxf(mm, __shfl_xor(mm, off));
      float es = 0.f;
      #pragma unroll
      for (int i = 0; i < 8; ++i) es += exp2_hw((v[i] - mm) * L2E_);
      #pragma unroll
      for (int off = 1; off <= 32; off <<= 1) es += __shfl_xor(es, off);
      const float logZ = mm + LN2_ * log2_hw(es);
      float* orow = out + ((size_t)(b * N_ + s0 + half * 16 + s)) * N_;
      #pragma unroll
      for (int i = 0; i < 8; ++i)
        orow[no[i]] = fmaxf(v[i] - logZ, NEG_BIG_);
    }
    __syncthreads();                            // protect logitsTb reuse
  }
}

// ---------------------------------------------------------------------------
extern "C" void kernel_launch(void* const* d_in, const int* in_sizes, int n_in,
                              void* d_out, int out_size, void* d_ws, size_t ws_size,
                              hipStream_t stream) {
  const float* emb   = (const float*)d_in[0];
  const int*   seq   = (const int*)d_in[1];
  const float* Wp    = (const float*)d_in[2];
  const float* Wnode = (const float*)d_in[3];
  const float* Wfix  = (const float*)d_in[4];
  const float* Wstep = (const float*)d_in[5];
  const float* Wout  = (const float*)d_in[6];
  float* out = (float*)d_out;

  ushortx* gK    = (ushortx*)d_ws;                       // 8388608 u16
  ushortx* gVt   = gK   + (size_t)8388608;               // 8388608 u16
  ushortx* lKt   = gVt  + (size_t)8388608;               // 8388608 u16
  ushortx* WfT   = lKt  + (size_t)8388608;               //   49152 u16
  ushortx* WsbT  = WfT  + (size_t)49152;                 //   16384 u16
  ushortx* Ksrt  = WsbT + (size_t)16384;                 //   65536 u16
  ushortx* n_or  = Ksrt + (size_t)65536;                 //   65536 u16
  ushortx* Qb0   = n_or + (size_t)65536;                 //   16384 u16
  float*   Abuf  = (float*)(Qb0 + (size_t)16384);        //   16384 f32

  const long long lp_elems = (long long)B_ * N_ * N_;
  const int tail = (int)((long long)out_size - lp_elems);

  prologue<<<512, 512, 0, stream>>>(emb, seq, Wp, Wnode, Wfix, Wstep, Wout,
                                    WfT, WsbT, Ksrt, n_or, Qb0, Abuf,
                                    out, tail > 0 ? tail : 0);
  proj_mfma<<<1024, 256, 0, stream>>>(emb, WfT, n_or, gK, gVt, lKt);
  decode_mfma<<<2048, 512, 0, stream>>>(gK, gVt, lKt, emb, seq, WsbT, Abuf,
                                        Qb0, Ksrt, n_or, out);
}